// Round 5
// baseline (2699.393 us; speedup 1.0000x reference)
//
#include <hip/hip_runtime.h>
#include <hip/hip_cooperative_groups.h>
#include <math.h>

namespace cg = cooperative_groups;

// ---------- helpers ----------

extern "C" __device__ float __ocml_native_exp2_f32(float);

__device__ __forceinline__ float sq3_rn(float ax, float ay, float az,
                                        float bx, float by, float bz) {
  float dx = __fsub_rn(ax, bx), dy = __fsub_rn(ay, by), dz = __fsub_rn(az, bz);
  return __fadd_rn(__fadd_rn(__fmul_rn(dx, dx), __fmul_rn(dy, dy)), __fmul_rn(dz, dz));
}

__device__ __forceinline__ float norm3_rn(float x, float y, float z) {
  return __fadd_rn(__fadd_rn(__fmul_rn(x, x), __fmul_rn(y, y)), __fmul_rn(z, z));
}

__device__ __forceinline__ float ex2(float x) {
#if __has_builtin(__builtin_amdgcn_exp2f)
  return __builtin_amdgcn_exp2f(x);
#else
  return __ocml_native_exp2_f32(x);
#endif
}
__device__ __forceinline__ float lg2(float x) { return __builtin_log2f(x); }

#define LOG2E 1.44269504088896340736f
#define LN2   0.69314718055994530942f

// sc[26]: emd1=0..3, emd2=4..7, cdp1=8, cdp2=12, cdt1=16, cdt2=20, u1=24, u2=25.
// Scatter: scr[s*256 + slot] (R13). DEPENDENCY (R14): gt-FPS rides only non-Y1 launches.
// R15/R16: fps_body must stay the R0 LDS-points loop (register restructure = 1.45x slower).
// R17 LESSON (measured): moving EMD2 halves out from under the FPS umbrella EXPOSES them
// (~10us each) to save cheaper EMD1 halves (~5us) — net loss. Keep CH2=41, all 20 EMD2
// halves + uniform riding FPS.
// R18 (this round): the EMD1 tail (20 launches + dist1 + dist2 + reduce, ~350us incl
// gaps) is launch-overhead-bound (~50us of VALU work). Replace with ONE cooperative
// kernel: 20 grid.sync rounds (64 sink blocks; 192 blocks drain dist2), then dist1,
// then in-kernel reduce_sc.

// ---------- pack + passthrough + zero sc/scr ----------
__global__ void pack4(const float* __restrict__ out1, const float* __restrict__ out2,
                      const float* __restrict__ gt,
                      float4* __restrict__ X1, float4* __restrict__ X2, float4* __restrict__ Y2,
                      float* __restrict__ outdst, float* __restrict__ sc,
                      float* __restrict__ scr) {
  int i = blockIdx.x * 256 + threadIdx.x;
  if (i < 26) sc[i] = 0.f;
  if (i < 6656) scr[i] = 0.f;
  if (i < 4096) {
    const float* s = out1 + 3 * (size_t)i;
    float x = s[0], y = s[1], z = s[2];
    X1[i] = make_float4(x, y, z, 0.f);
    float* d = outdst + 3 * (size_t)i;
    d[0] = x; d[1] = y; d[2] = z;
  } else if (i < 20480) {
    int j = i - 4096;
    const float* s = out2 + 3 * (size_t)j;
    float x = s[0], y = s[1], z = s[2];
    X2[j] = make_float4(x, y, z, 0.f);
    float* d = outdst + 12288 + 3 * (size_t)j;
    d[0] = x; d[1] = y; d[2] = z;
  } else if (i < 36864) {
    int j = i - 20480;
    const float* s = gt + 3 * (size_t)j;
    Y2[j] = make_float4(s[0], s[1], s[2], 0.f);
  }
}

// ---------- FPS body: R6-proven 512-thread core + chunk/resume (R0 verbatim) ----------
template <int PPT>
__device__ void fps_body(const float* __restrict__ xb, int it0, int it1,
                         float* __restrict__ dlws, int* __restrict__ farws,
                         bool fresh, bool save,
                         float4* __restrict__ y1g, int* __restrict__ idxg,
                         float* spx, float* spy, float* spz,
                         int* obs, unsigned long long* red /*[16]*/) {
  int t = threadIdx.x;  // 0..511
  float rx[PPT], ry[PPT], rz[PPT], dl[PPT];
#pragma unroll
  for (int j = 0; j < PPT; ++j) {
    int n = t + (j << 9);
    float x = xb[3 * n], y = xb[3 * n + 1], z = xb[3 * n + 2];
    rx[j] = x; ry[j] = y; rz[j] = z;
    spx[n] = x; spy[n] = y; spz[n] = z;
  }
  if (fresh) {
#pragma unroll
    for (int j = 0; j < PPT; ++j) dl[j] = 1e10f;
  } else {
#pragma unroll
    for (int j = 0; j < PPT; ++j) dl[j] = dlws[(j << 9) + t];
  }
  int far = fresh ? 0 : farws[0];
  if (fresh && t == 0) {
    if (y1g) y1g[0] = make_float4(xb[0], xb[1], xb[2], 0.f);
    if (idxg) idxg[0] = 0;
  }
  __syncthreads();
  int lane = t & 63, wid = t >> 6;
  for (int it = it0; it < it1; ++it) {
    float cx = spx[far], cy = spy[far], cz = spz[far];  // wave-uniform broadcast reads
    float bv = -1.f; int bi = 0;
#pragma unroll
    for (int j = 0; j < PPT; ++j) {
      int n = t + (j << 9);
      float d = sq3_rn(rx[j], ry[j], rz[j], cx, cy, cz);
      float dn = fminf(dl[j], d);
      dl[j] = dn;
      bool c = dn > bv;  // strict > with ascending n => first-index local tiebreak
      bv = c ? dn : bv;
      bi = c ? n : bi;
    }
    unsigned long long key =
        ((unsigned long long)__float_as_uint(bv) << 32) | (unsigned)(0x7fffffff - bi);
#pragma unroll
    for (int off = 1; off <= 32; off <<= 1) {
      unsigned long long k2 = __shfl_xor(key, off);
      key = (k2 > key) ? k2 : key;
    }
    unsigned long long* rb = red + ((it & 1) << 3);
    if (lane == 0) rb[wid] = key;
    __syncthreads();
    unsigned long long k0 = rb[0], k1 = rb[1], k2 = rb[2], k3 = rb[3];
    unsigned long long k4 = rb[4], k5 = rb[5], k6 = rb[6], k7 = rb[7];
    unsigned long long a0 = k0 > k1 ? k0 : k1, a1 = k2 > k3 ? k2 : k3;
    unsigned long long a2 = k4 > k5 ? k4 : k5, a3 = k6 > k7 ? k6 : k7;
    unsigned long long b0 = a0 > a1 ? a0 : a1, b1 = a2 > a3 ? a2 : a3;
    unsigned long long kk = b0 > b1 ? b0 : b1;
    far = 0x7fffffff - (int)(unsigned)(kk & 0xffffffffULL);  // all threads agree
    if (t == 0) obs[it - it0] = far;
  }
  __syncthreads();
  int cnt = it1 - it0;
  if (y1g)
    for (int i = t; i < cnt; i += 512) {
      int j = obs[i];
      y1g[it0 + i] = make_float4(spx[j], spy[j], spz[j], 0.f);
    }
  if (idxg)
    for (int i = t; i < cnt; i += 512) idxg[it0 + i] = obs[i];
  if (save) {
#pragma unroll
    for (int j = 0; j < PPT; ++j) dlws[(j << 9) + t] = dl[j];
    if (t == 0) farws[0] = far;
  }
}

// ---------- chamfer: 2 rows per wave, scattered atomics ----------
__device__ void chamfer_wave2(const float4* __restrict__ A, const float4* __restrict__ Bp,
                              int Na, int Nb, int w, int lane,
                              float* __restrict__ scr, int sp_s, int st_s, int slot) {
  int rows = Na >> 1;
  int b = w / rows, i0 = (w - b * rows) << 1;
  float4 a0 = A[(size_t)b * Na + i0];
  float4 a1 = A[(size_t)b * Na + i0 + 1];
  const float4* pb = Bp + (size_t)b * Nb;
  float mn0 = 3.4e38f, mn1 = 3.4e38f;
  for (int j = lane; j < Nb; j += 64) {
    float4 p = pb[j];
    float dx0 = p.x - a0.x, dy0 = p.y - a0.y, dz0 = p.z - a0.z;
    mn0 = fminf(mn0, dx0 * dx0 + dy0 * dy0 + dz0 * dz0);
    float dx1 = p.x - a1.x, dy1 = p.y - a1.y, dz1 = p.z - a1.z;
    mn1 = fminf(mn1, dx1 * dx1 + dy1 * dy1 + dz1 * dz1);
  }
  for (int off = 32; off; off >>= 1) {
    mn0 = fminf(mn0, __shfl_xor(mn0, off));
    mn1 = fminf(mn1, __shfl_xor(mn1, off));
  }
  if (lane == 0) {
    atomicAdd(&scr[(sp_s + b) * 256 + slot], 0.5f * (sqrtf(mn0) + sqrtf(mn1)) * (1.f / (float)Na));
    atomicAdd(&scr[(st_s + b) * 256 + slot], (mn0 + mn1) * (1.f / (float)Na));
  }
}

// ---------- mega1: gt-FPS chunk0 + out1/out2 FPS + all chamfer (512-thr, 55KB) ----------
struct Mega1Args {
  const float *gt, *out1, *out2;
  const float4 *X1, *X2, *Y2;
  float4* Y1;
  float* dlws; int* farws;
  int* idx_u1; int* idx_u2;
  float* scr;
  int gt_it1;
};

__global__ __launch_bounds__(512) void mega1(Mega1Args A) {
  __shared__ __align__(16) unsigned char sm[55296];  // FPS-tail-bound; LDS cap irrelevant (R1-R3)
  float* spx = (float*)sm;
  float* spy = (float*)(sm + 16384);
  float* spz = (float*)(sm + 32768);
  int* obs = (int*)(sm + 49152);
  unsigned long long* red = (unsigned long long*)(sm + 53248);
  int blk = blockIdx.x;
  int t = threadIdx.x;
  if (blk < 4) {  // gt-FPS chunk0 [1, gt_it1), fresh, save
    __builtin_amdgcn_s_setprio(3);  // serial critical path
    int b = blk;
    fps_body<8>(A.gt + (size_t)b * 4096 * 3, 1, A.gt_it1,
                A.dlws + (size_t)b * 4096, A.farws + b, true, true,
                A.Y1 + (size_t)b * 1024, nullptr, spx, spy, spz, obs, red);
    return;
  }
  if (blk < 8) {  // out2-FPS full 204
    __builtin_amdgcn_s_setprio(3);
    int b = blk - 4;
    fps_body<8>(A.out2 + (size_t)b * 4096 * 3, 1, 204, nullptr, nullptr, true, false,
                nullptr, A.idx_u2 + (size_t)b * 204, spx, spy, spz, obs, red);
    return;
  }
  if (blk < 12) {  // out1-FPS full 51
    __builtin_amdgcn_s_setprio(3);
    int b = blk - 8;
    fps_body<2>(A.out1 + (size_t)b * 1024 * 3, 1, 51, nullptr, nullptr, true, false,
                nullptr, A.idx_u1 + (size_t)b * 51, spx, spy, spz, obs, red);
    return;
  }
  __builtin_amdgcn_s_setprio(0);
  int lane = t & 63, wid = t >> 6;
  int slot = ((blk << 3) + wid) & 255;
  int wt = (blk - 12) * 8 + wid;  // 26624 wave-tasks over 3328 blocks
  if (wt < 8192)        chamfer_wave2(A.Y2, A.X1, 4096, 1024, wt,         lane, A.scr, 8, 16, slot);
  else if (wt < 10240)  chamfer_wave2(A.X1, A.Y2, 1024, 4096, wt - 8192,  lane, A.scr, 8, 16, slot);
  else if (wt < 18432)  chamfer_wave2(A.Y2, A.X2, 4096, 4096, wt - 10240, lane, A.scr, 12, 20, slot);
  else                  chamfer_wave2(A.X2, A.Y2, 4096, 4096, wt - 18432, lane, A.scr, 12, 20, slot);
}

// ---------- sink wave: 8 outputs, no-max (bounded args), SoA LDS tile (R13-validated) ----------
__device__ void sink_wave8(float4* __restrict__ Pout, const float4* __restrict__ Pred,
                           int N, float c, int w0, float ie2, float eps_ln2,
                           float* xs, float* ys, float* zs, float* ws4, int nthr) {
  int t = threadIdx.x, lane = t & 63;
  int b = w0 / N, o0 = w0 - b * N;
  float qx[8], qy[8], qz[8], Bc[8], S[8];
  float two_ie = 2.f * ie2;
#pragma unroll
  for (int r = 0; r < 8; ++r) {
    float4 m = Pout[(size_t)b * N + o0 + r];
    qx[r] = two_ie * m.x; qy[r] = two_ie * m.y; qz[r] = two_ie * m.z;
    Bc[r] = -ie2 * (m.x * m.x + m.y * m.y + m.z * m.z);
    S[r] = 0.f;
  }
  const float4* Rb = Pred + (size_t)b * N;
  for (int base = 0; base < N; base += 1024) {
    __syncthreads();
    for (int i = t; i < 1024; i += nthr) {
      float4 p = Rb[base + i];
      xs[i] = p.x; ys[i] = p.y; zs[i] = p.z;
      ws4[i] = (p.w - fmaf(p.z, p.z, fmaf(p.y, p.y, p.x * p.x))) * ie2;
    }
    __syncthreads();
#pragma unroll
    for (int k = 0; k < 16; ++k) {
      int idx = lane + (k << 6);
      float px = xs[idx], py = ys[idx], pz = zs[idx], pw = ws4[idx];
#pragma unroll
      for (int r = 0; r < 8; ++r)
        S[r] += ex2(fmaf(pz, qz[r], fmaf(py, qy[r], fmaf(px, qx[r], pw + Bc[r]))));
    }
  }
#pragma unroll
  for (int r = 0; r < 8; ++r)
    for (int off = 32; off; off >>= 1) S[r] += __shfl_xor(S[r], off);
  if (lane == 0) {
#pragma unroll
    for (int r = 0; r < 8; ++r)
      Pout[(size_t)b * N + o0 + r].w = c - eps_ln2 * lg2(S[r]);
  }
}

// ---------- EMD distance wave (scattered) ----------
__device__ void emd_dist_wave(const float4* __restrict__ X, const float4* __restrict__ Y,
                              int N, int task, int lane, float ie2,
                              float* __restrict__ scr, int base_s, int slot) {
  int b = task / N, n = task - b * N;
  float4 mine = X[(size_t)b * N + n];
  const float4* Yb = Y + (size_t)b * N;
  float acc = 0.f;
  for (int m = lane; m < N; m += 64) {
    float4 p = Yb[m];
    float dx = p.x - mine.x, dy = p.y - mine.y, dz = p.z - mine.z;
    float d = dx * dx + dy * dy + dz * dz;
    acc += ex2((mine.w + p.w - d) * ie2) * d;
  }
  for (int off = 32; off; off >>= 1) acc += __shfl_xor(acc, off);
  if (lane == 0)
    atomicAdd(&scr[(base_s + b) * 256 + slot], sqrtf((float)N * acc) * (1.f / (float)N));
}

// ---------- uniform loss wave (bit-exact discrete path, scattered) ----------
struct UniP {
  float r2[5]; int ns[5]; float exden[5]; float exlen[5]; float wg[5];
};

__device__ void uniform_wave(const float* __restrict__ pcd, const int* __restrict__ fpsidx,
                             int N, int npoint, const UniP& P, int task, int lane,
                             int* sel, float* gx, float* gy, float* gz,
                             float* __restrict__ scr, int us, int slot) {
  int pi = task % 5;
  int tmp = task / 5;
  int s = tmp % npoint;
  int b = tmp / npoint;
  int nsample = P.ns[pi];
  float r2 = P.r2[pi];
  const float* Pb = pcd + (size_t)b * N * 3;
  int sidx = fpsidx[b * npoint + s];
  float sx = Pb[3 * sidx], sy = Pb[3 * sidx + 1], sz = Pb[3 * sidx + 2];
  float snorm = norm3_rn(sx, sy, sz);

  int cnt = 0;
  for (int base = 0; base < N && cnt < nsample; base += 64) {
    int n = base + lane;
    float pxn = Pb[3 * n], pyn = Pb[3 * n + 1], pzn = Pb[3 * n + 2];
    float pn2 = norm3_rn(pxn, pyn, pzn);
    float dot = __fadd_rn(__fadd_rn(__fmul_rn(sx, pxn), __fmul_rn(sy, pyn)), __fmul_rn(sz, pzn));
    float d2 = fmaxf(__fsub_rn(__fadd_rn(snorm, pn2), __fmul_rn(2.f, dot)), 0.f);
    unsigned long long bal = __ballot(d2 < r2);
    while (bal && cnt < nsample) {
      int bit = __builtin_ctzll(bal);
      if (lane == 0) sel[cnt] = base + bit;
      cnt++;
      bal &= bal - 1;
    }
  }
  if (lane < nsample) {
    int gi = (lane < cnt) ? sel[lane] : sel[0];
    gx[lane] = Pb[3 * gi]; gy[lane] = Pb[3 * gi + 1]; gz[lane] = Pb[3 * gi + 2];
  }
  float dval = 0.f;
  if (lane < nsample) {
    float mn = 1e10f;
    for (int k = 0; k < nsample; ++k) {
      if (k == lane) continue;
      float dx = gx[lane] - gx[k], dy = gy[lane] - gy[k], dz = gz[lane] - gz[k];
      float d = dx * dx + dy * dy + dz * dz;
      mn = fminf(mn, d);
    }
    dval = sqrtf(fabsf(mn + 1e-8f));
  }
  for (int off = 32; off; off >>= 1) dval += __shfl_xor(dval, off);
  if (lane == 0) {
    float mean_d = dval / (float)nsample;
    float diff = mean_d - P.exlen[pi];
    atomicAdd(&scr[us * 256 + slot], diff * diff / P.exden[pi] * P.wg[pi]);
  }
}

// ---------- sinku: [nfps FPS] + sink + uniform slice (R1-proven schedule) ----------
// 512-thr, 55KB LDS (2 blocks/CU). GRID MUST BE <= 512 BLOCKS (one co-residency round).
struct SinkUArgs {
  float4* Pout; const float4* Pred; int N; float c; int nfps, nsink;
  const float* gt; float* dlws; int* farws; float4* Y1;
  int it0, it1;
  const float *o1raw, *o2raw;
  const int *iu1, *iu2;
  UniP P1, P2;
  int uni0;
  float* scr;
  float ie2, eps_ln2;
};

__global__ __launch_bounds__(512) void sinku(SinkUArgs A) {
  __shared__ __align__(16) unsigned char sm[55296];
  int blk = blockIdx.x;
  int t = threadIdx.x, lane = t & 63, wid = t >> 6;
  if (blk < A.nfps) {  // gt-FPS chunk (resume) — only on launches that don't touch Y1
    __builtin_amdgcn_s_setprio(3);
    float* spx = (float*)sm;
    float* spy = (float*)(sm + 16384);
    float* spz = (float*)(sm + 32768);
    int* obs = (int*)(sm + 49152);
    unsigned long long* red = (unsigned long long*)(sm + 53248);
    int b = blk;
    fps_body<8>(A.gt + (size_t)b * 4096 * 3, A.it0, A.it1,
                A.dlws + (size_t)b * 4096, A.farws + b, false, true,
                A.Y1 + (size_t)b * 1024, nullptr, spx, spy, spz, obs, red);
    return;
  }
  __builtin_amdgcn_s_setprio(0);
  float* smf = (float*)sm;
  if (blk < A.nfps + A.nsink) {
    int sblk = blk - A.nfps;
    int w0 = ((sblk << 3) + wid) << 3;  // 8 waves x 8 outputs = 64 outputs/block
    sink_wave8(A.Pout, A.Pred, A.N, A.c, w0, A.ie2, A.eps_ln2,
               smf, smf + 1024, smf + 2048, smf + 3072, 512);
    return;
  }
  int slot = ((blk << 3) + wid) & 255;
  // uniform: 8 tasks per block
  int ublk = blk - (A.nfps + A.nsink);
  int task = (A.uni0 + ublk) * 8 + wid;
  float* sl = smf + wid * 256;
  int* sel = (int*)sl;
  float* gx = smf + 2048 + wid * 256;
  float* gy = smf + 4096 + wid * 256;
  float* gz = smf + 6144 + wid * 256;
  if (task < 1020)
    uniform_wave(A.o1raw, A.iu1, 1024, 51, A.P1, task, lane, sel, gx, gy, gz, A.scr, 24, slot);
  else if (task < 5100)
    uniform_wave(A.o2raw, A.iu2, 4096, 204, A.P2, task - 1020, lane, sel, gx, gy, gz, A.scr, 25, slot);
}

// ---------- cooperative tail: EMD1 chain + dist2 + dist1 + reduce_sc ----------
// 256 blocks x 512 thr, 16KB LDS -> all co-resident (1 block/CU). 21 grid syncs.
struct TailArgs {
  float4 *X1, *Y1;
  const float4 *X2, *Y2;
  float c1, ie2, eps_ln2;
  float* scr;
  float* sc;
};

__global__ __launch_bounds__(512) void emd1_tail(TailArgs A) {
  cg::grid_group grid = cg::this_grid();
  __shared__ __align__(16) float smf[4096];  // sink tile (16KB); reused as r4 for reduce
  int blk = blockIdx.x, t = threadIdx.x, lane = t & 63, wid = t >> 6;
  int slot = ((blk << 3) + wid) & 255;
  for (int h = 0; h < 20; ++h) {
    if (blk < 64) {  // EMD1 half h: g-update (Pout=Y1) then f-update (Pout=X1), alternating
      float4* Pout = (h & 1) ? A.X1 : A.Y1;
      const float4* Pred = (h & 1) ? (const float4*)A.Y1 : (const float4*)A.X1;
      int w0 = ((blk << 3) + wid) << 3;  // 64 outputs/block, 64 blocks = 4x1024
      sink_wave8(Pout, Pred, 1024, A.c1, w0, A.ie2, A.eps_ln2,
                 smf, smf + 1024, smf + 2048, smf + 3072, 512);
    } else {  // drain dist2 (final X2/Y2 ready before this kernel): 16384 wave-tasks
      int task = h * 1536 + (blk - 64) * 8 + wid;
      if (task < 16384)
        emd_dist_wave(A.X2, A.Y2, 4096, task, lane, A.ie2, A.scr, 4, slot);
    }
    __threadfence();
    grid.sync();
  }
  // dist1: 4096 wave-tasks over 2048 waves (2 each); slot = task&255 matches R1 mapping
  {
    int w = (blk << 3) + wid;  // 0..2047
    emd_dist_wave(A.X1, A.Y1, 1024, w, lane, A.ie2, A.scr, 0, w & 255);
    emd_dist_wave(A.X1, A.Y1, 1024, w + 2048, lane, A.ie2, A.scr, 0, (w + 2048) & 255);
  }
  __threadfence();
  grid.sync();
  if (blk == 0) {  // reduce_sc, byte-equivalent (all 512 threads participate in barriers)
    float* r4 = smf;
    for (int s = 0; s < 26; ++s) {
      float v = (t < 256) ? A.scr[s * 256 + t] : 0.f;
      for (int off = 32; off; off >>= 1) v += __shfl_xor(v, off);
      if (lane == 0 && t < 256) r4[wid] = v;
      __syncthreads();
      if (t == 0) A.sc[s] = r4[0] + r4[1] + r4[2] + r4[3];
      __syncthreads();
    }
  }
}

// ---------- host launch ----------

extern "C" void kernel_launch(void* const* d_in, const int* in_sizes, int n_in,
                              void* d_out, int out_size, void* d_ws, size_t ws_size,
                              hipStream_t stream) {
  const float* out1 = (const float*)d_in[0];  // (4,1024,3)
  const float* out2 = (const float*)d_in[1];  // (4,4096,3)
  const float* gt   = (const float*)d_in[2];  // (4,4096,3)
  float* out = (float*)d_out;
  const int B = 4, N1 = 1024, N2 = 4096;

  char* ws = (char*)d_ws;
  float*  dl_ws  = (float*)(ws + 0);            // 64K gt-FPS dl state
  int*    far_ws = (int*)(ws + 64 * 1024);
  int*    idx_u1 = (int*)(ws + 66 * 1024);
  int*    idx_u2 = (int*)(ws + 68 * 1024);
  float*  scr    = (float*)(ws + 80 * 1024);    // 26x256 floats
  float4* X1 = (float4*)(ws + 112 * 1024);      // 64K  out1 + f1
  float4* Y1 = (float4*)(ws + 176 * 1024);      // 64K  gtfps + g1
  float4* X2 = (float4*)(ws + 240 * 1024);      // 256K out2 + f2
  float4* Y2 = (float4*)(ws + 496 * 1024);      // 256K gt + g2 -> ends 752K

  float* sc = out + (size_t)B * N1 * 3 + (size_t)B * N2 * 3;

  pack4<<<(36864 + 255) / 256, 256, 0, stream>>>(out1, out2, gt, X1, X2, Y2, out, sc, scr);

  const float ie2 = 200.0f * LOG2E;
  const float eps_ln2 = 0.005f * LN2;
  float c1 = (float)(0.005 * (-log((double)N1)));
  float c2 = (float)(0.005 * (-log((double)N2)));

  // gt-FPS schedule: mega1 [1,204); EMD2 launch k (k=0..19): [204+41k, +41) -> 1024.
  const int GT_M = 204, CH2 = 41;

  Mega1Args M1;
  M1.gt = gt; M1.out1 = out1; M1.out2 = out2;
  M1.X1 = X1; M1.X2 = X2; M1.Y2 = Y2; M1.Y1 = Y1;
  M1.dlws = dl_ws; M1.farws = far_ws;
  M1.idx_u1 = idx_u1; M1.idx_u2 = idx_u2; M1.scr = scr;
  M1.gt_it1 = GT_M;
  mega1<<<12 + 3328, 512, 0, stream>>>(M1);

  // uniform params
  const double PCT[5] = {0.004, 0.006, 0.008, 0.01, 0.012};
  int np1 = 51, np2 = 204;
  UniP P1, P2;
  for (int k = 0; k < 5; ++k) {
    double p = PCT[k];
    {
      int ns = (int)((double)N1 * p);
      double r = sqrt(p * 1.0);
      double el = sqrt(M_PI * 1.0 * p / (double)ns);
      P1.r2[k] = (float)(r * r); P1.ns[k] = ns;
      P1.exlen[k] = (float)el;   P1.exden[k] = (float)(el + 1e-8);
      P1.wg[k] = (float)((p * 100.0) * (p * 100.0) / (5.0 * (double)B * (double)np1));
    }
    {
      int ns = (int)((double)N2 * p);
      double r = sqrt(p * 1.0);
      double el = sqrt(M_PI * 1.0 * p / (double)ns);
      P2.r2[k] = (float)(r * r); P2.ns[k] = ns;
      P2.exlen[k] = (float)el;   P2.exden[k] = (float)(el + 1e-8);
      P2.wg[k] = (float)((p * 100.0) * (p * 100.0) / (5.0 * (double)B * (double)np2));
    }
  }

  SinkUArgs SA;
  SA.gt = gt; SA.dlws = dl_ws; SA.farws = far_ws; SA.Y1 = Y1;
  SA.ie2 = ie2; SA.eps_ln2 = eps_ln2;
  SA.o1raw = out1; SA.o2raw = out2; SA.iu1 = idx_u1; SA.iu2 = idx_u2;
  SA.P1 = P1; SA.P2 = P2; SA.scr = scr;

  // EMD2 chain (R1 schedule): 20 launches, 4 FPS[41] + 256 sink + uniform slices.
  // Grid <= 4+256+213 = 473 <= 512 (one co-residency round at 55KB).
  const int UNI_BLOCKS = 638;
  SA.N = N2; SA.c = c2; SA.nfps = 4; SA.nsink = 256;
  int chunk = 0, uni_done = 0;
  for (int it = 0; it < 10; ++it) {
    for (int half = 0; half < 2; ++half) {
      SA.Pout = half ? X2 : Y2;
      SA.Pred = half ? (const float4*)Y2 : (const float4*)X2;
      SA.it0 = GT_M + CH2 * chunk;
      SA.it1 = SA.it0 + CH2;
      chunk++;
      int un = 0;
      if (uni_done < UNI_BLOCKS) un = (UNI_BLOCKS - uni_done < 213) ? UNI_BLOCKS - uni_done : 213;
      SA.uni0 = uni_done;
      uni_done += un;
      sinku<<<4 + 256 + un, 512, 0, stream>>>(SA);
    }
  }

  // Cooperative tail: EMD1 20 halves + dist2 drain + dist1 + reduce_sc, one launch.
  TailArgs TA;
  TA.X1 = X1; TA.Y1 = Y1; TA.X2 = X2; TA.Y2 = Y2;
  TA.c1 = c1; TA.ie2 = ie2; TA.eps_ln2 = eps_ln2;
  TA.scr = scr; TA.sc = sc;
  void* targs[] = {(void*)&TA};
  hipLaunchCooperativeKernel((void*)emd1_tail, dim3(256), dim3(512), targs, 0, stream);
}

// Round 6
// 1330.376 us; speedup vs baseline: 2.0290x; 2.0290x over previous
//
#include <hip/hip_runtime.h>
#include <math.h>

// ---------- helpers ----------

extern "C" __device__ float __ocml_native_exp2_f32(float);

__device__ __forceinline__ float sq3_rn(float ax, float ay, float az,
                                        float bx, float by, float bz) {
  float dx = __fsub_rn(ax, bx), dy = __fsub_rn(ay, by), dz = __fsub_rn(az, bz);
  return __fadd_rn(__fadd_rn(__fmul_rn(dx, dx), __fmul_rn(dy, dy)), __fmul_rn(dz, dz));
}

__device__ __forceinline__ float norm3_rn(float x, float y, float z) {
  return __fadd_rn(__fadd_rn(__fmul_rn(x, x), __fmul_rn(y, y)), __fmul_rn(z, z));
}

__device__ __forceinline__ float ex2(float x) {
#if __has_builtin(__builtin_amdgcn_exp2f)
  return __builtin_amdgcn_exp2f(x);
#else
  return __ocml_native_exp2_f32(x);
#endif
}
__device__ __forceinline__ float lg2(float x) { return __builtin_log2f(x); }

#define LOG2E 1.44269504088896340736f
#define LN2   0.69314718055994530942f

// sc[26]: emd1=0..3, emd2=4..7, cdp1=8, cdp2=12, cdt1=16, cdt2=20, u1=24, u2=25.
// Scatter: scr[s*256 + slot] (R13). DEPENDENCY (R14): gt-FPS rides only non-Y1 launches.
// R15/R16: fps_body must stay the R0 LDS-points loop (register restructure = 1.45x slower,
//          measured twice). R17: sink halves must stay under the FPS umbrella (moving them
//          out exposes ~10us each — measured). R18: cg::grid.sync costs ~80us/sync on
//          MI355X (8-XCD L2 writeback + cross-XCD spin) — grid-wide sync is ruled out.
// R19 (this round): device code byte-identical to the 1202us baseline. ONE host change:
// gt-FPS rides only EMD2 launches 0-9 at CH2=82 (launches 10-19 nfps=0) — halves the
// dl-state save/restore cycles and the count of FPS-gated launches, amortizing the
// measured ~10us/launch resume+dispatch overhead. Sink halves/uniform untouched.

// ---------- pack + passthrough + zero sc/scr ----------
__global__ void pack4(const float* __restrict__ out1, const float* __restrict__ out2,
                      const float* __restrict__ gt,
                      float4* __restrict__ X1, float4* __restrict__ X2, float4* __restrict__ Y2,
                      float* __restrict__ outdst, float* __restrict__ sc,
                      float* __restrict__ scr) {
  int i = blockIdx.x * 256 + threadIdx.x;
  if (i < 26) sc[i] = 0.f;
  if (i < 6656) scr[i] = 0.f;
  if (i < 4096) {
    const float* s = out1 + 3 * (size_t)i;
    float x = s[0], y = s[1], z = s[2];
    X1[i] = make_float4(x, y, z, 0.f);
    float* d = outdst + 3 * (size_t)i;
    d[0] = x; d[1] = y; d[2] = z;
  } else if (i < 20480) {
    int j = i - 4096;
    const float* s = out2 + 3 * (size_t)j;
    float x = s[0], y = s[1], z = s[2];
    X2[j] = make_float4(x, y, z, 0.f);
    float* d = outdst + 12288 + 3 * (size_t)j;
    d[0] = x; d[1] = y; d[2] = z;
  } else if (i < 36864) {
    int j = i - 20480;
    const float* s = gt + 3 * (size_t)j;
    Y2[j] = make_float4(s[0], s[1], s[2], 0.f);
  }
}

// ---------- FPS body: R6-proven 512-thread core + chunk/resume (R0 verbatim) ----------
template <int PPT>
__device__ void fps_body(const float* __restrict__ xb, int it0, int it1,
                         float* __restrict__ dlws, int* __restrict__ farws,
                         bool fresh, bool save,
                         float4* __restrict__ y1g, int* __restrict__ idxg,
                         float* spx, float* spy, float* spz,
                         int* obs, unsigned long long* red /*[16]*/) {
  int t = threadIdx.x;  // 0..511
  float rx[PPT], ry[PPT], rz[PPT], dl[PPT];
#pragma unroll
  for (int j = 0; j < PPT; ++j) {
    int n = t + (j << 9);
    float x = xb[3 * n], y = xb[3 * n + 1], z = xb[3 * n + 2];
    rx[j] = x; ry[j] = y; rz[j] = z;
    spx[n] = x; spy[n] = y; spz[n] = z;
  }
  if (fresh) {
#pragma unroll
    for (int j = 0; j < PPT; ++j) dl[j] = 1e10f;
  } else {
#pragma unroll
    for (int j = 0; j < PPT; ++j) dl[j] = dlws[(j << 9) + t];
  }
  int far = fresh ? 0 : farws[0];
  if (fresh && t == 0) {
    if (y1g) y1g[0] = make_float4(xb[0], xb[1], xb[2], 0.f);
    if (idxg) idxg[0] = 0;
  }
  __syncthreads();
  int lane = t & 63, wid = t >> 6;
  for (int it = it0; it < it1; ++it) {
    float cx = spx[far], cy = spy[far], cz = spz[far];  // wave-uniform broadcast reads
    float bv = -1.f; int bi = 0;
#pragma unroll
    for (int j = 0; j < PPT; ++j) {
      int n = t + (j << 9);
      float d = sq3_rn(rx[j], ry[j], rz[j], cx, cy, cz);
      float dn = fminf(dl[j], d);
      dl[j] = dn;
      bool c = dn > bv;  // strict > with ascending n => first-index local tiebreak
      bv = c ? dn : bv;
      bi = c ? n : bi;
    }
    unsigned long long key =
        ((unsigned long long)__float_as_uint(bv) << 32) | (unsigned)(0x7fffffff - bi);
#pragma unroll
    for (int off = 1; off <= 32; off <<= 1) {
      unsigned long long k2 = __shfl_xor(key, off);
      key = (k2 > key) ? k2 : key;
    }
    unsigned long long* rb = red + ((it & 1) << 3);
    if (lane == 0) rb[wid] = key;
    __syncthreads();
    unsigned long long k0 = rb[0], k1 = rb[1], k2 = rb[2], k3 = rb[3];
    unsigned long long k4 = rb[4], k5 = rb[5], k6 = rb[6], k7 = rb[7];
    unsigned long long a0 = k0 > k1 ? k0 : k1, a1 = k2 > k3 ? k2 : k3;
    unsigned long long a2 = k4 > k5 ? k4 : k5, a3 = k6 > k7 ? k6 : k7;
    unsigned long long b0 = a0 > a1 ? a0 : a1, b1 = a2 > a3 ? a2 : a3;
    unsigned long long kk = b0 > b1 ? b0 : b1;
    far = 0x7fffffff - (int)(unsigned)(kk & 0xffffffffULL);  // all threads agree
    if (t == 0) obs[it - it0] = far;
  }
  __syncthreads();
  int cnt = it1 - it0;
  if (y1g)
    for (int i = t; i < cnt; i += 512) {
      int j = obs[i];
      y1g[it0 + i] = make_float4(spx[j], spy[j], spz[j], 0.f);
    }
  if (idxg)
    for (int i = t; i < cnt; i += 512) idxg[it0 + i] = obs[i];
  if (save) {
#pragma unroll
    for (int j = 0; j < PPT; ++j) dlws[(j << 9) + t] = dl[j];
    if (t == 0) farws[0] = far;
  }
}

// ---------- chamfer: 2 rows per wave, scattered atomics ----------
__device__ void chamfer_wave2(const float4* __restrict__ A, const float4* __restrict__ Bp,
                              int Na, int Nb, int w, int lane,
                              float* __restrict__ scr, int sp_s, int st_s, int slot) {
  int rows = Na >> 1;
  int b = w / rows, i0 = (w - b * rows) << 1;
  float4 a0 = A[(size_t)b * Na + i0];
  float4 a1 = A[(size_t)b * Na + i0 + 1];
  const float4* pb = Bp + (size_t)b * Nb;
  float mn0 = 3.4e38f, mn1 = 3.4e38f;
  for (int j = lane; j < Nb; j += 64) {
    float4 p = pb[j];
    float dx0 = p.x - a0.x, dy0 = p.y - a0.y, dz0 = p.z - a0.z;
    mn0 = fminf(mn0, dx0 * dx0 + dy0 * dy0 + dz0 * dz0);
    float dx1 = p.x - a1.x, dy1 = p.y - a1.y, dz1 = p.z - a1.z;
    mn1 = fminf(mn1, dx1 * dx1 + dy1 * dy1 + dz1 * dz1);
  }
  for (int off = 32; off; off >>= 1) {
    mn0 = fminf(mn0, __shfl_xor(mn0, off));
    mn1 = fminf(mn1, __shfl_xor(mn1, off));
  }
  if (lane == 0) {
    atomicAdd(&scr[(sp_s + b) * 256 + slot], 0.5f * (sqrtf(mn0) + sqrtf(mn1)) * (1.f / (float)Na));
    atomicAdd(&scr[(st_s + b) * 256 + slot], (mn0 + mn1) * (1.f / (float)Na));
  }
}

// ---------- mega1: gt-FPS chunk0 + out1/out2 FPS + all chamfer (512-thr, 55KB) ----------
struct Mega1Args {
  const float *gt, *out1, *out2;
  const float4 *X1, *X2, *Y2;
  float4* Y1;
  float* dlws; int* farws;
  int* idx_u1; int* idx_u2;
  float* scr;
  int gt_it1;
};

__global__ __launch_bounds__(512) void mega1(Mega1Args A) {
  __shared__ __align__(16) unsigned char sm[55296];
  float* spx = (float*)sm;
  float* spy = (float*)(sm + 16384);
  float* spz = (float*)(sm + 32768);
  int* obs = (int*)(sm + 49152);
  unsigned long long* red = (unsigned long long*)(sm + 53248);
  int blk = blockIdx.x;
  int t = threadIdx.x;
  if (blk < 4) {  // gt-FPS chunk0 [1, gt_it1), fresh, save
    __builtin_amdgcn_s_setprio(3);  // serial critical path
    int b = blk;
    fps_body<8>(A.gt + (size_t)b * 4096 * 3, 1, A.gt_it1,
                A.dlws + (size_t)b * 4096, A.farws + b, true, true,
                A.Y1 + (size_t)b * 1024, nullptr, spx, spy, spz, obs, red);
    return;
  }
  if (blk < 8) {  // out2-FPS full 204
    __builtin_amdgcn_s_setprio(3);
    int b = blk - 4;
    fps_body<8>(A.out2 + (size_t)b * 4096 * 3, 1, 204, nullptr, nullptr, true, false,
                nullptr, A.idx_u2 + (size_t)b * 204, spx, spy, spz, obs, red);
    return;
  }
  if (blk < 12) {  // out1-FPS full 51
    __builtin_amdgcn_s_setprio(3);
    int b = blk - 8;
    fps_body<2>(A.out1 + (size_t)b * 1024 * 3, 1, 51, nullptr, nullptr, true, false,
                nullptr, A.idx_u1 + (size_t)b * 51, spx, spy, spz, obs, red);
    return;
  }
  __builtin_amdgcn_s_setprio(0);
  int lane = t & 63, wid = t >> 6;
  int slot = ((blk << 3) + wid) & 255;
  int wt = (blk - 12) * 8 + wid;  // 26624 wave-tasks over 3328 blocks
  if (wt < 8192)        chamfer_wave2(A.Y2, A.X1, 4096, 1024, wt,         lane, A.scr, 8, 16, slot);
  else if (wt < 10240)  chamfer_wave2(A.X1, A.Y2, 1024, 4096, wt - 8192,  lane, A.scr, 8, 16, slot);
  else if (wt < 18432)  chamfer_wave2(A.Y2, A.X2, 4096, 4096, wt - 10240, lane, A.scr, 12, 20, slot);
  else                  chamfer_wave2(A.X2, A.Y2, 4096, 4096, wt - 18432, lane, A.scr, 12, 20, slot);
}

// ---------- sink wave: 8 outputs, no-max (bounded args), SoA LDS tile (R13-validated) ----------
__device__ void sink_wave8(float4* __restrict__ Pout, const float4* __restrict__ Pred,
                           int N, float c, int w0, float ie2, float eps_ln2,
                           float* xs, float* ys, float* zs, float* ws4, int nthr) {
  int t = threadIdx.x, lane = t & 63;
  int b = w0 / N, o0 = w0 - b * N;
  float qx[8], qy[8], qz[8], Bc[8], S[8];
  float two_ie = 2.f * ie2;
#pragma unroll
  for (int r = 0; r < 8; ++r) {
    float4 m = Pout[(size_t)b * N + o0 + r];
    qx[r] = two_ie * m.x; qy[r] = two_ie * m.y; qz[r] = two_ie * m.z;
    Bc[r] = -ie2 * (m.x * m.x + m.y * m.y + m.z * m.z);
    S[r] = 0.f;
  }
  const float4* Rb = Pred + (size_t)b * N;
  for (int base = 0; base < N; base += 1024) {
    __syncthreads();
    for (int i = t; i < 1024; i += nthr) {
      float4 p = Rb[base + i];
      xs[i] = p.x; ys[i] = p.y; zs[i] = p.z;
      ws4[i] = (p.w - fmaf(p.z, p.z, fmaf(p.y, p.y, p.x * p.x))) * ie2;
    }
    __syncthreads();
#pragma unroll
    for (int k = 0; k < 16; ++k) {
      int idx = lane + (k << 6);
      float px = xs[idx], py = ys[idx], pz = zs[idx], pw = ws4[idx];
#pragma unroll
      for (int r = 0; r < 8; ++r)
        S[r] += ex2(fmaf(pz, qz[r], fmaf(py, qy[r], fmaf(px, qx[r], pw + Bc[r]))));
    }
  }
#pragma unroll
  for (int r = 0; r < 8; ++r)
    for (int off = 32; off; off >>= 1) S[r] += __shfl_xor(S[r], off);
  if (lane == 0) {
#pragma unroll
    for (int r = 0; r < 8; ++r)
      Pout[(size_t)b * N + o0 + r].w = c - eps_ln2 * lg2(S[r]);
  }
}

// ---------- EMD distance wave (scattered) ----------
__device__ void emd_dist_wave(const float4* __restrict__ X, const float4* __restrict__ Y,
                              int N, int task, int lane, float ie2,
                              float* __restrict__ scr, int base_s, int slot) {
  int b = task / N, n = task - b * N;
  float4 mine = X[(size_t)b * N + n];
  const float4* Yb = Y + (size_t)b * N;
  float acc = 0.f;
  for (int m = lane; m < N; m += 64) {
    float4 p = Yb[m];
    float dx = p.x - mine.x, dy = p.y - mine.y, dz = p.z - mine.z;
    float d = dx * dx + dy * dy + dz * dz;
    acc += ex2((mine.w + p.w - d) * ie2) * d;
  }
  for (int off = 32; off; off >>= 1) acc += __shfl_xor(acc, off);
  if (lane == 0)
    atomicAdd(&scr[(base_s + b) * 256 + slot], sqrtf((float)N * acc) * (1.f / (float)N));
}

// ---------- uniform loss wave (bit-exact discrete path, scattered) ----------
struct UniP {
  float r2[5]; int ns[5]; float exden[5]; float exlen[5]; float wg[5];
};

__device__ void uniform_wave(const float* __restrict__ pcd, const int* __restrict__ fpsidx,
                             int N, int npoint, const UniP& P, int task, int lane,
                             int* sel, float* gx, float* gy, float* gz,
                             float* __restrict__ scr, int us, int slot) {
  int pi = task % 5;
  int tmp = task / 5;
  int s = tmp % npoint;
  int b = tmp / npoint;
  int nsample = P.ns[pi];
  float r2 = P.r2[pi];
  const float* Pb = pcd + (size_t)b * N * 3;
  int sidx = fpsidx[b * npoint + s];
  float sx = Pb[3 * sidx], sy = Pb[3 * sidx + 1], sz = Pb[3 * sidx + 2];
  float snorm = norm3_rn(sx, sy, sz);

  int cnt = 0;
  for (int base = 0; base < N && cnt < nsample; base += 64) {
    int n = base + lane;
    float pxn = Pb[3 * n], pyn = Pb[3 * n + 1], pzn = Pb[3 * n + 2];
    float pn2 = norm3_rn(pxn, pyn, pzn);
    float dot = __fadd_rn(__fadd_rn(__fmul_rn(sx, pxn), __fmul_rn(sy, pyn)), __fmul_rn(sz, pzn));
    float d2 = fmaxf(__fsub_rn(__fadd_rn(snorm, pn2), __fmul_rn(2.f, dot)), 0.f);
    unsigned long long bal = __ballot(d2 < r2);
    while (bal && cnt < nsample) {
      int bit = __builtin_ctzll(bal);
      if (lane == 0) sel[cnt] = base + bit;
      cnt++;
      bal &= bal - 1;
    }
  }
  if (lane < nsample) {
    int gi = (lane < cnt) ? sel[lane] : sel[0];
    gx[lane] = Pb[3 * gi]; gy[lane] = Pb[3 * gi + 1]; gz[lane] = Pb[3 * gi + 2];
  }
  float dval = 0.f;
  if (lane < nsample) {
    float mn = 1e10f;
    for (int k = 0; k < nsample; ++k) {
      if (k == lane) continue;
      float dx = gx[lane] - gx[k], dy = gy[lane] - gy[k], dz = gz[lane] - gz[k];
      float d = dx * dx + dy * dy + dz * dz;
      mn = fminf(mn, d);
    }
    dval = sqrtf(fabsf(mn + 1e-8f));
  }
  for (int off = 32; off; off >>= 1) dval += __shfl_xor(dval, off);
  if (lane == 0) {
    float mean_d = dval / (float)nsample;
    float diff = mean_d - P.exlen[pi];
    atomicAdd(&scr[us * 256 + slot], diff * diff / P.exden[pi] * P.wg[pi]);
  }
}

// ---------- sinku: [nfps FPS chunks] + sink half-pass + dist2 slice + uniform slice ----------
// 512-thr, 55KB LDS (2 blocks/CU). GRID MUST BE <= 512 BLOCKS (one co-residency round).
struct SinkUArgs {
  float4* Pout; const float4* Pred; int N; float c; int nfps, nsink;
  const float* gt; float* dlws; int* farws; float4* Y1;
  int it0, it1;
  const float4 *dX, *dY; int dN, dbase, d2_0, d2_n;
  const float *o1raw, *o2raw;
  const int *iu1, *iu2;
  UniP P1, P2;
  int uni0;
  float* scr;
  float ie2, eps_ln2;
};

__global__ __launch_bounds__(512) void sinku(SinkUArgs A) {
  __shared__ __align__(16) unsigned char sm[55296];
  int blk = blockIdx.x;
  int t = threadIdx.x, lane = t & 63, wid = t >> 6;
  if (blk < A.nfps) {  // gt-FPS chunk (resume) — only on launches that don't touch Y1
    __builtin_amdgcn_s_setprio(3);
    float* spx = (float*)sm;
    float* spy = (float*)(sm + 16384);
    float* spz = (float*)(sm + 32768);
    int* obs = (int*)(sm + 49152);
    unsigned long long* red = (unsigned long long*)(sm + 53248);
    int b = blk;
    fps_body<8>(A.gt + (size_t)b * 4096 * 3, A.it0, A.it1,
                A.dlws + (size_t)b * 4096, A.farws + b, false, true,
                A.Y1 + (size_t)b * 1024, nullptr, spx, spy, spz, obs, red);
    return;
  }
  __builtin_amdgcn_s_setprio(0);
  float* smf = (float*)sm;
  if (blk < A.nfps + A.nsink) {
    int sblk = blk - A.nfps;
    int w0 = ((sblk << 3) + wid) << 3;  // 8 waves x 8 outputs = 64 outputs/block
    sink_wave8(A.Pout, A.Pred, A.N, A.c, w0, A.ie2, A.eps_ln2,
               smf, smf + 1024, smf + 2048, smf + 3072, 512);
    return;
  }
  int slot = ((blk << 3) + wid) & 255;
  if (blk < A.nfps + A.nsink + A.d2_n) {
    int dblk = A.d2_0 + (blk - A.nfps - A.nsink);
    emd_dist_wave(A.dX, A.dY, A.dN, dblk * 8 + wid, lane, A.ie2, A.scr, A.dbase, slot);
    return;
  }
  // uniform: 8 tasks per block
  int ublk = blk - (A.nfps + A.nsink + A.d2_n);
  int task = (A.uni0 + ublk) * 8 + wid;
  float* sl = smf + wid * 256;
  int* sel = (int*)sl;
  float* gx = smf + 2048 + wid * 256;
  float* gy = smf + 4096 + wid * 256;
  float* gz = smf + 6144 + wid * 256;
  if (task < 1020)
    uniform_wave(A.o1raw, A.iu1, 1024, 51, A.P1, task, lane, sel, gx, gy, gz, A.scr, 24, slot);
  else if (task < 5100)
    uniform_wave(A.o2raw, A.iu2, 4096, 204, A.P2, task - 1020, lane, sel, gx, gy, gz, A.scr, 25, slot);
}

// ---------- dist1 (scattered) ----------
__global__ __launch_bounds__(256) void dist1(const float4* __restrict__ X1,
                                             const float4* __restrict__ Y1,
                                             float* __restrict__ scr, float ie2) {
  int lane = threadIdx.x & 63, wid = threadIdx.x >> 6;
  int slot = ((blockIdx.x << 2) + wid) & 255;
  emd_dist_wave(X1, Y1, 1024, blockIdx.x * 4 + wid, lane, ie2, scr, 0, slot);
}

// ---------- final reduce: scr -> sc ----------
__global__ __launch_bounds__(256) void reduce_sc(const float* __restrict__ scr,
                                                 float* __restrict__ sc) {
  __shared__ float r4[4];
  int t = threadIdx.x, lane = t & 63, wid = t >> 6;
  for (int s = 0; s < 26; ++s) {
    float v = scr[s * 256 + t];
    for (int off = 32; off; off >>= 1) v += __shfl_xor(v, off);
    if (lane == 0) r4[wid] = v;
    __syncthreads();
    if (t == 0) sc[s] = r4[0] + r4[1] + r4[2] + r4[3];
    __syncthreads();
  }
}

// ---------- host launch ----------

extern "C" void kernel_launch(void* const* d_in, const int* in_sizes, int n_in,
                              void* d_out, int out_size, void* d_ws, size_t ws_size,
                              hipStream_t stream) {
  const float* out1 = (const float*)d_in[0];  // (4,1024,3)
  const float* out2 = (const float*)d_in[1];  // (4,4096,3)
  const float* gt   = (const float*)d_in[2];  // (4,4096,3)
  float* out = (float*)d_out;
  const int B = 4, N1 = 1024, N2 = 4096;

  char* ws = (char*)d_ws;
  float*  dl_ws  = (float*)(ws + 0);            // 64K gt-FPS dl state
  int*    far_ws = (int*)(ws + 64 * 1024);
  int*    idx_u1 = (int*)(ws + 66 * 1024);
  int*    idx_u2 = (int*)(ws + 68 * 1024);
  float*  scr    = (float*)(ws + 80 * 1024);    // 26x256 floats
  float4* X1 = (float4*)(ws + 112 * 1024);      // 64K  out1 + f1
  float4* Y1 = (float4*)(ws + 176 * 1024);      // 64K  gtfps + g1
  float4* X2 = (float4*)(ws + 240 * 1024);      // 256K out2 + f2
  float4* Y2 = (float4*)(ws + 496 * 1024);      // 256K gt + g2 -> ends 752K

  float* sc = out + (size_t)B * N1 * 3 + (size_t)B * N2 * 3;

  pack4<<<(36864 + 255) / 256, 256, 0, stream>>>(out1, out2, gt, X1, X2, Y2, out, sc, scr);

  const float ie2 = 200.0f * LOG2E;
  const float eps_ln2 = 0.005f * LN2;
  float c1 = (float)(0.005 * (-log((double)N1)));
  float c2 = (float)(0.005 * (-log((double)N2)));

  // gt-FPS schedule: mega1 [1,204); EMD2 launch k (k=0..9): [204+82k, +82) -> 1024.
  // Launches 10-19 carry no FPS (R19). EMD1 chain carries NO FPS (R14).
  const int GT_M = 204, CH2 = 82;

  Mega1Args M1;
  M1.gt = gt; M1.out1 = out1; M1.out2 = out2;
  M1.X1 = X1; M1.X2 = X2; M1.Y2 = Y2; M1.Y1 = Y1;
  M1.dlws = dl_ws; M1.farws = far_ws;
  M1.idx_u1 = idx_u1; M1.idx_u2 = idx_u2; M1.scr = scr;
  M1.gt_it1 = GT_M;
  mega1<<<12 + 3328, 512, 0, stream>>>(M1);

  // uniform params
  const double PCT[5] = {0.004, 0.006, 0.008, 0.01, 0.012};
  int np1 = 51, np2 = 204;
  UniP P1, P2;
  for (int k = 0; k < 5; ++k) {
    double p = PCT[k];
    {
      int ns = (int)((double)N1 * p);
      double r = sqrt(p * 1.0);
      double el = sqrt(M_PI * 1.0 * p / (double)ns);
      P1.r2[k] = (float)(r * r); P1.ns[k] = ns;
      P1.exlen[k] = (float)el;   P1.exden[k] = (float)(el + 1e-8);
      P1.wg[k] = (float)((p * 100.0) * (p * 100.0) / (5.0 * (double)B * (double)np1));
    }
    {
      int ns = (int)((double)N2 * p);
      double r = sqrt(p * 1.0);
      double el = sqrt(M_PI * 1.0 * p / (double)ns);
      P2.r2[k] = (float)(r * r); P2.ns[k] = ns;
      P2.exlen[k] = (float)el;   P2.exden[k] = (float)(el + 1e-8);
      P2.wg[k] = (float)((p * 100.0) * (p * 100.0) / (5.0 * (double)B * (double)np2));
    }
  }

  SinkUArgs SA;
  SA.gt = gt; SA.dlws = dl_ws; SA.farws = far_ws; SA.Y1 = Y1;
  SA.ie2 = ie2; SA.eps_ln2 = eps_ln2;
  SA.o1raw = out1; SA.o2raw = out2; SA.iu1 = idx_u1; SA.iu2 = idx_u2;
  SA.P1 = P1; SA.P2 = P2; SA.scr = scr;
  SA.dX = X2; SA.dY = Y2; SA.dN = N2; SA.dbase = 4;

  // EMD2 chain: 20 launches. First 10 carry FPS chunks of 82 iters (204 -> 1024);
  // last 10 carry none. All 20 sink halves + uniform slices unchanged (R17).
  // Grid <= 4+256+213 = 473 <= 512 (one co-residency round at 55KB).
  const int UNI_BLOCKS = 638;
  SA.N = N2; SA.c = c2; SA.nsink = 256; SA.d2_0 = 0; SA.d2_n = 0;
  int uni_done = 0;
  for (int k = 0; k < 20; ++k) {
    int half = k & 1;
    SA.Pout = half ? X2 : Y2;
    SA.Pred = half ? (const float4*)Y2 : (const float4*)X2;
    if (k < 10) {
      SA.nfps = 4;
      SA.it0 = GT_M + CH2 * k;
      SA.it1 = SA.it0 + CH2;  // k=9 ends at 1024
    } else {
      SA.nfps = 0;
      SA.it0 = 0; SA.it1 = 0;
    }
    int un = 0;
    if (uni_done < UNI_BLOCKS) un = (UNI_BLOCKS - uni_done < 213) ? UNI_BLOCKS - uni_done : 213;
    SA.uni0 = uni_done;
    uni_done += un;
    sinku<<<SA.nfps + 256 + un, 512, 0, stream>>>(SA);
  }

  // EMD1 chain: Y1 complete now. 20 launches, 0 FPS + 64 sink blocks + dist2 slices.
  SA.N = N1; SA.c = c1; SA.nfps = 0; SA.nsink = 64;
  SA.it0 = 0; SA.it1 = 0;
  int d2_done = 0;
  for (int it = 0; it < 10; ++it) {
    for (int half = 0; half < 2; ++half) {
      SA.Pout = half ? X1 : Y1;
      SA.Pred = half ? (const float4*)Y1 : (const float4*)X1;
      int dn = (2048 - d2_done < 103) ? 2048 - d2_done : 103;
      SA.d2_0 = d2_done; SA.d2_n = dn;
      d2_done += dn;
      SA.uni0 = UNI_BLOCKS;  // none
      sinku<<<64 + dn, 512, 0, stream>>>(SA);
    }
  }

  dist1<<<1024, 256, 0, stream>>>(X1, Y1, scr, ie2);
  reduce_sc<<<1, 256, 0, stream>>>(scr, sc);
}

// Round 7
// 1259.583 us; speedup vs baseline: 2.1431x; 1.0562x over previous
//
#include <hip/hip_runtime.h>
#include <math.h>

// ---------- helpers ----------

extern "C" __device__ float __ocml_native_exp2_f32(float);

__device__ __forceinline__ float sq3_rn(float ax, float ay, float az,
                                        float bx, float by, float bz) {
  float dx = __fsub_rn(ax, bx), dy = __fsub_rn(ay, by), dz = __fsub_rn(az, bz);
  return __fadd_rn(__fadd_rn(__fmul_rn(dx, dx), __fmul_rn(dy, dy)), __fmul_rn(dz, dz));
}

__device__ __forceinline__ float norm3_rn(float x, float y, float z) {
  return __fadd_rn(__fadd_rn(__fmul_rn(x, x), __fmul_rn(y, y)), __fmul_rn(z, z));
}

__device__ __forceinline__ float ex2(float x) {
#if __has_builtin(__builtin_amdgcn_exp2f)
  return __builtin_amdgcn_exp2f(x);
#else
  return __ocml_native_exp2_f32(x);
#endif
}
__device__ __forceinline__ float lg2(float x) { return __builtin_log2f(x); }

#define LOG2E 1.44269504088896340736f
#define LN2   0.69314718055994530942f

// sc[26]: emd1=0..3, emd2=4..7, cdp1=8, cdp2=12, cdt1=16, cdt2=20, u1=24, u2=25.
// Scatter: scr[s*256 + slot] (R13). DEPENDENCY (R14): gt-FPS rides only non-Y1 launches.
// R15/R16: fps_body must stay the R0 LDS-points loop (register restructure = 1.45x slower,
//          measured twice). R17: sink halves must stay under the FPS umbrella (moving them
//          out exposes ~10-11us each — measured TWICE, R4 & R6). R18: cg grid.sync costs
//          ~80us on MI355X — ruled out. R19/R6: per-launch FPS fixed cost is SMALL (<~3us);
//          chain is work-bound; CH2=41 x 20 is the measured optimum schedule.
// R20 (this round): value-identical load-path change — FPS reads points from the
// float4-packed clouds (Y2/X2/X1, built by pack4) instead of stride-3 raw arrays:
// 8 coalesced 16B loads/thread vs 24 scalar. Sink writes only .w words; FPS reads
// only .xyz — word-granular, no race. Uniform spread 32/launch (was 213 on 0-2).

// ---------- pack + passthrough + zero sc/scr ----------
__global__ void pack4(const float* __restrict__ out1, const float* __restrict__ out2,
                      const float* __restrict__ gt,
                      float4* __restrict__ X1, float4* __restrict__ X2, float4* __restrict__ Y2,
                      float* __restrict__ outdst, float* __restrict__ sc,
                      float* __restrict__ scr) {
  int i = blockIdx.x * 256 + threadIdx.x;
  if (i < 26) sc[i] = 0.f;
  if (i < 6656) scr[i] = 0.f;
  if (i < 4096) {
    const float* s = out1 + 3 * (size_t)i;
    float x = s[0], y = s[1], z = s[2];
    X1[i] = make_float4(x, y, z, 0.f);
    float* d = outdst + 3 * (size_t)i;
    d[0] = x; d[1] = y; d[2] = z;
  } else if (i < 20480) {
    int j = i - 4096;
    const float* s = out2 + 3 * (size_t)j;
    float x = s[0], y = s[1], z = s[2];
    X2[j] = make_float4(x, y, z, 0.f);
    float* d = outdst + 12288 + 3 * (size_t)j;
    d[0] = x; d[1] = y; d[2] = z;
  } else if (i < 36864) {
    int j = i - 20480;
    const float* s = gt + 3 * (size_t)j;
    Y2[j] = make_float4(s[0], s[1], s[2], 0.f);
  }
}

// ---------- FPS body: R6-proven 512-thread core + chunk/resume ----------
// R20: points loaded from packed float4 cloud (xyz identical to raw; .w ignored).
template <int PPT>
__device__ void fps_body(const float4* __restrict__ xb4, int it0, int it1,
                         float* __restrict__ dlws, int* __restrict__ farws,
                         bool fresh, bool save,
                         float4* __restrict__ y1g, int* __restrict__ idxg,
                         float* spx, float* spy, float* spz,
                         int* obs, unsigned long long* red /*[16]*/) {
  int t = threadIdx.x;  // 0..511
  float rx[PPT], ry[PPT], rz[PPT], dl[PPT];
#pragma unroll
  for (int j = 0; j < PPT; ++j) {
    int n = t + (j << 9);
    float4 p = xb4[n];  // coalesced 16B load
    rx[j] = p.x; ry[j] = p.y; rz[j] = p.z;
    spx[n] = p.x; spy[n] = p.y; spz[n] = p.z;
  }
  if (fresh) {
#pragma unroll
    for (int j = 0; j < PPT; ++j) dl[j] = 1e10f;
  } else {
#pragma unroll
    for (int j = 0; j < PPT; ++j) dl[j] = dlws[(j << 9) + t];
  }
  int far = fresh ? 0 : farws[0];
  if (fresh && t == 0) {
    float4 p0 = xb4[0];
    if (y1g) y1g[0] = make_float4(p0.x, p0.y, p0.z, 0.f);
    if (idxg) idxg[0] = 0;
  }
  __syncthreads();
  int lane = t & 63, wid = t >> 6;
  for (int it = it0; it < it1; ++it) {
    float cx = spx[far], cy = spy[far], cz = spz[far];  // wave-uniform broadcast reads
    float bv = -1.f; int bi = 0;
#pragma unroll
    for (int j = 0; j < PPT; ++j) {
      int n = t + (j << 9);
      float d = sq3_rn(rx[j], ry[j], rz[j], cx, cy, cz);
      float dn = fminf(dl[j], d);
      dl[j] = dn;
      bool c = dn > bv;  // strict > with ascending n => first-index local tiebreak
      bv = c ? dn : bv;
      bi = c ? n : bi;
    }
    unsigned long long key =
        ((unsigned long long)__float_as_uint(bv) << 32) | (unsigned)(0x7fffffff - bi);
#pragma unroll
    for (int off = 1; off <= 32; off <<= 1) {
      unsigned long long k2 = __shfl_xor(key, off);
      key = (k2 > key) ? k2 : key;
    }
    unsigned long long* rb = red + ((it & 1) << 3);
    if (lane == 0) rb[wid] = key;
    __syncthreads();
    unsigned long long k0 = rb[0], k1 = rb[1], k2 = rb[2], k3 = rb[3];
    unsigned long long k4 = rb[4], k5 = rb[5], k6 = rb[6], k7 = rb[7];
    unsigned long long a0 = k0 > k1 ? k0 : k1, a1 = k2 > k3 ? k2 : k3;
    unsigned long long a2 = k4 > k5 ? k4 : k5, a3 = k6 > k7 ? k6 : k7;
    unsigned long long b0 = a0 > a1 ? a0 : a1, b1 = a2 > a3 ? a2 : a3;
    unsigned long long kk = b0 > b1 ? b0 : b1;
    far = 0x7fffffff - (int)(unsigned)(kk & 0xffffffffULL);  // all threads agree
    if (t == 0) obs[it - it0] = far;
  }
  __syncthreads();
  int cnt = it1 - it0;
  if (y1g)
    for (int i = t; i < cnt; i += 512) {
      int j = obs[i];
      y1g[it0 + i] = make_float4(spx[j], spy[j], spz[j], 0.f);
    }
  if (idxg)
    for (int i = t; i < cnt; i += 512) idxg[it0 + i] = obs[i];
  if (save) {
#pragma unroll
    for (int j = 0; j < PPT; ++j) dlws[(j << 9) + t] = dl[j];
    if (t == 0) farws[0] = far;
  }
}

// ---------- chamfer: 2 rows per wave, scattered atomics ----------
__device__ void chamfer_wave2(const float4* __restrict__ A, const float4* __restrict__ Bp,
                              int Na, int Nb, int w, int lane,
                              float* __restrict__ scr, int sp_s, int st_s, int slot) {
  int rows = Na >> 1;
  int b = w / rows, i0 = (w - b * rows) << 1;
  float4 a0 = A[(size_t)b * Na + i0];
  float4 a1 = A[(size_t)b * Na + i0 + 1];
  const float4* pb = Bp + (size_t)b * Nb;
  float mn0 = 3.4e38f, mn1 = 3.4e38f;
  for (int j = lane; j < Nb; j += 64) {
    float4 p = pb[j];
    float dx0 = p.x - a0.x, dy0 = p.y - a0.y, dz0 = p.z - a0.z;
    mn0 = fminf(mn0, dx0 * dx0 + dy0 * dy0 + dz0 * dz0);
    float dx1 = p.x - a1.x, dy1 = p.y - a1.y, dz1 = p.z - a1.z;
    mn1 = fminf(mn1, dx1 * dx1 + dy1 * dy1 + dz1 * dz1);
  }
  for (int off = 32; off; off >>= 1) {
    mn0 = fminf(mn0, __shfl_xor(mn0, off));
    mn1 = fminf(mn1, __shfl_xor(mn1, off));
  }
  if (lane == 0) {
    atomicAdd(&scr[(sp_s + b) * 256 + slot], 0.5f * (sqrtf(mn0) + sqrtf(mn1)) * (1.f / (float)Na));
    atomicAdd(&scr[(st_s + b) * 256 + slot], (mn0 + mn1) * (1.f / (float)Na));
  }
}

// ---------- mega1: gt-FPS chunk0 + out1/out2 FPS + all chamfer (512-thr, 55KB) ----------
struct Mega1Args {
  const float4 *X1, *X2, *Y2;
  float4* Y1;
  float* dlws; int* farws;
  int* idx_u1; int* idx_u2;
  float* scr;
  int gt_it1;
};

__global__ __launch_bounds__(512) void mega1(Mega1Args A) {
  __shared__ __align__(16) unsigned char sm[55296];
  float* spx = (float*)sm;
  float* spy = (float*)(sm + 16384);
  float* spz = (float*)(sm + 32768);
  int* obs = (int*)(sm + 49152);
  unsigned long long* red = (unsigned long long*)(sm + 53248);
  int blk = blockIdx.x;
  int t = threadIdx.x;
  if (blk < 4) {  // gt-FPS chunk0 [1, gt_it1), fresh, save — points from packed Y2
    __builtin_amdgcn_s_setprio(3);  // serial critical path
    int b = blk;
    fps_body<8>(A.Y2 + (size_t)b * 4096, 1, A.gt_it1,
                A.dlws + (size_t)b * 4096, A.farws + b, true, true,
                A.Y1 + (size_t)b * 1024, nullptr, spx, spy, spz, obs, red);
    return;
  }
  if (blk < 8) {  // out2-FPS full 204 — points from packed X2
    __builtin_amdgcn_s_setprio(3);
    int b = blk - 4;
    fps_body<8>(A.X2 + (size_t)b * 4096, 1, 204, nullptr, nullptr, true, false,
                nullptr, A.idx_u2 + (size_t)b * 204, spx, spy, spz, obs, red);
    return;
  }
  if (blk < 12) {  // out1-FPS full 51 — points from packed X1
    __builtin_amdgcn_s_setprio(3);
    int b = blk - 8;
    fps_body<2>(A.X1 + (size_t)b * 1024, 1, 51, nullptr, nullptr, true, false,
                nullptr, A.idx_u1 + (size_t)b * 51, spx, spy, spz, obs, red);
    return;
  }
  __builtin_amdgcn_s_setprio(0);
  int lane = t & 63, wid = t >> 6;
  int slot = ((blk << 3) + wid) & 255;
  int wt = (blk - 12) * 8 + wid;  // 26624 wave-tasks over 3328 blocks
  if (wt < 8192)        chamfer_wave2(A.Y2, A.X1, 4096, 1024, wt,         lane, A.scr, 8, 16, slot);
  else if (wt < 10240)  chamfer_wave2(A.X1, A.Y2, 1024, 4096, wt - 8192,  lane, A.scr, 8, 16, slot);
  else if (wt < 18432)  chamfer_wave2(A.Y2, A.X2, 4096, 4096, wt - 10240, lane, A.scr, 12, 20, slot);
  else                  chamfer_wave2(A.X2, A.Y2, 4096, 4096, wt - 18432, lane, A.scr, 12, 20, slot);
}

// ---------- sink wave: 8 outputs, no-max (bounded args), SoA LDS tile (R13-validated) ----------
__device__ void sink_wave8(float4* __restrict__ Pout, const float4* __restrict__ Pred,
                           int N, float c, int w0, float ie2, float eps_ln2,
                           float* xs, float* ys, float* zs, float* ws4, int nthr) {
  int t = threadIdx.x, lane = t & 63;
  int b = w0 / N, o0 = w0 - b * N;
  float qx[8], qy[8], qz[8], Bc[8], S[8];
  float two_ie = 2.f * ie2;
#pragma unroll
  for (int r = 0; r < 8; ++r) {
    float4 m = Pout[(size_t)b * N + o0 + r];
    qx[r] = two_ie * m.x; qy[r] = two_ie * m.y; qz[r] = two_ie * m.z;
    Bc[r] = -ie2 * (m.x * m.x + m.y * m.y + m.z * m.z);
    S[r] = 0.f;
  }
  const float4* Rb = Pred + (size_t)b * N;
  for (int base = 0; base < N; base += 1024) {
    __syncthreads();
    for (int i = t; i < 1024; i += nthr) {
      float4 p = Rb[base + i];
      xs[i] = p.x; ys[i] = p.y; zs[i] = p.z;
      ws4[i] = (p.w - fmaf(p.z, p.z, fmaf(p.y, p.y, p.x * p.x))) * ie2;
    }
    __syncthreads();
#pragma unroll
    for (int k = 0; k < 16; ++k) {
      int idx = lane + (k << 6);
      float px = xs[idx], py = ys[idx], pz = zs[idx], pw = ws4[idx];
#pragma unroll
      for (int r = 0; r < 8; ++r)
        S[r] += ex2(fmaf(pz, qz[r], fmaf(py, qy[r], fmaf(px, qx[r], pw + Bc[r]))));
    }
  }
#pragma unroll
  for (int r = 0; r < 8; ++r)
    for (int off = 32; off; off >>= 1) S[r] += __shfl_xor(S[r], off);
  if (lane == 0) {
#pragma unroll
    for (int r = 0; r < 8; ++r)
      Pout[(size_t)b * N + o0 + r].w = c - eps_ln2 * lg2(S[r]);
  }
}

// ---------- EMD distance wave (scattered) ----------
__device__ void emd_dist_wave(const float4* __restrict__ X, const float4* __restrict__ Y,
                              int N, int task, int lane, float ie2,
                              float* __restrict__ scr, int base_s, int slot) {
  int b = task / N, n = task - b * N;
  float4 mine = X[(size_t)b * N + n];
  const float4* Yb = Y + (size_t)b * N;
  float acc = 0.f;
  for (int m = lane; m < N; m += 64) {
    float4 p = Yb[m];
    float dx = p.x - mine.x, dy = p.y - mine.y, dz = p.z - mine.z;
    float d = dx * dx + dy * dy + dz * dz;
    acc += ex2((mine.w + p.w - d) * ie2) * d;
  }
  for (int off = 32; off; off >>= 1) acc += __shfl_xor(acc, off);
  if (lane == 0)
    atomicAdd(&scr[(base_s + b) * 256 + slot], sqrtf((float)N * acc) * (1.f / (float)N));
}

// ---------- uniform loss wave (bit-exact discrete path, scattered) ----------
struct UniP {
  float r2[5]; int ns[5]; float exden[5]; float exlen[5]; float wg[5];
};

__device__ void uniform_wave(const float* __restrict__ pcd, const int* __restrict__ fpsidx,
                             int N, int npoint, const UniP& P, int task, int lane,
                             int* sel, float* gx, float* gy, float* gz,
                             float* __restrict__ scr, int us, int slot) {
  int pi = task % 5;
  int tmp = task / 5;
  int s = tmp % npoint;
  int b = tmp / npoint;
  int nsample = P.ns[pi];
  float r2 = P.r2[pi];
  const float* Pb = pcd + (size_t)b * N * 3;
  int sidx = fpsidx[b * npoint + s];
  float sx = Pb[3 * sidx], sy = Pb[3 * sidx + 1], sz = Pb[3 * sidx + 2];
  float snorm = norm3_rn(sx, sy, sz);

  int cnt = 0;
  for (int base = 0; base < N && cnt < nsample; base += 64) {
    int n = base + lane;
    float pxn = Pb[3 * n], pyn = Pb[3 * n + 1], pzn = Pb[3 * n + 2];
    float pn2 = norm3_rn(pxn, pyn, pzn);
    float dot = __fadd_rn(__fadd_rn(__fmul_rn(sx, pxn), __fmul_rn(sy, pyn)), __fmul_rn(sz, pzn));
    float d2 = fmaxf(__fsub_rn(__fadd_rn(snorm, pn2), __fmul_rn(2.f, dot)), 0.f);
    unsigned long long bal = __ballot(d2 < r2);
    while (bal && cnt < nsample) {
      int bit = __builtin_ctzll(bal);
      if (lane == 0) sel[cnt] = base + bit;
      cnt++;
      bal &= bal - 1;
    }
  }
  if (lane < nsample) {
    int gi = (lane < cnt) ? sel[lane] : sel[0];
    gx[lane] = Pb[3 * gi]; gy[lane] = Pb[3 * gi + 1]; gz[lane] = Pb[3 * gi + 2];
  }
  float dval = 0.f;
  if (lane < nsample) {
    float mn = 1e10f;
    for (int k = 0; k < nsample; ++k) {
      if (k == lane) continue;
      float dx = gx[lane] - gx[k], dy = gy[lane] - gy[k], dz = gz[lane] - gz[k];
      float d = dx * dx + dy * dy + dz * dz;
      mn = fminf(mn, d);
    }
    dval = sqrtf(fabsf(mn + 1e-8f));
  }
  for (int off = 32; off; off >>= 1) dval += __shfl_xor(dval, off);
  if (lane == 0) {
    float mean_d = dval / (float)nsample;
    float diff = mean_d - P.exlen[pi];
    atomicAdd(&scr[us * 256 + slot], diff * diff / P.exden[pi] * P.wg[pi]);
  }
}

// ---------- sinku: [nfps FPS chunks] + sink half-pass + dist2 slice + uniform slice ----------
// 512-thr, 55KB LDS (2 blocks/CU). GRID MUST BE <= 512 BLOCKS (one co-residency round).
struct SinkUArgs {
  float4* Pout; const float4* Pred; int N; float c; int nfps, nsink;
  const float4* gt4;  // packed gt (= Y2); FPS reads .xyz only
  float* dlws; int* farws; float4* Y1;
  int it0, it1;
  const float4 *dX, *dY; int dN, dbase, d2_0, d2_n;
  const float *o1raw, *o2raw;
  const int *iu1, *iu2;
  UniP P1, P2;
  int uni0;
  float* scr;
  float ie2, eps_ln2;
};

__global__ __launch_bounds__(512) void sinku(SinkUArgs A) {
  __shared__ __align__(16) unsigned char sm[55296];
  int blk = blockIdx.x;
  int t = threadIdx.x, lane = t & 63, wid = t >> 6;
  if (blk < A.nfps) {  // gt-FPS chunk (resume) — only on launches that don't touch Y1
    __builtin_amdgcn_s_setprio(3);
    float* spx = (float*)sm;
    float* spy = (float*)(sm + 16384);
    float* spz = (float*)(sm + 32768);
    int* obs = (int*)(sm + 49152);
    unsigned long long* red = (unsigned long long*)(sm + 53248);
    int b = blk;
    fps_body<8>(A.gt4 + (size_t)b * 4096, A.it0, A.it1,
                A.dlws + (size_t)b * 4096, A.farws + b, false, true,
                A.Y1 + (size_t)b * 1024, nullptr, spx, spy, spz, obs, red);
    return;
  }
  __builtin_amdgcn_s_setprio(0);
  float* smf = (float*)sm;
  if (blk < A.nfps + A.nsink) {
    int sblk = blk - A.nfps;
    int w0 = ((sblk << 3) + wid) << 3;  // 8 waves x 8 outputs = 64 outputs/block
    sink_wave8(A.Pout, A.Pred, A.N, A.c, w0, A.ie2, A.eps_ln2,
               smf, smf + 1024, smf + 2048, smf + 3072, 512);
    return;
  }
  int slot = ((blk << 3) + wid) & 255;
  if (blk < A.nfps + A.nsink + A.d2_n) {
    int dblk = A.d2_0 + (blk - A.nfps - A.nsink);
    emd_dist_wave(A.dX, A.dY, A.dN, dblk * 8 + wid, lane, A.ie2, A.scr, A.dbase, slot);
    return;
  }
  // uniform: 8 tasks per block
  int ublk = blk - (A.nfps + A.nsink + A.d2_n);
  int task = (A.uni0 + ublk) * 8 + wid;
  float* sl = smf + wid * 256;
  int* sel = (int*)sl;
  float* gx = smf + 2048 + wid * 256;
  float* gy = smf + 4096 + wid * 256;
  float* gz = smf + 6144 + wid * 256;
  if (task < 1020)
    uniform_wave(A.o1raw, A.iu1, 1024, 51, A.P1, task, lane, sel, gx, gy, gz, A.scr, 24, slot);
  else if (task < 5100)
    uniform_wave(A.o2raw, A.iu2, 4096, 204, A.P2, task - 1020, lane, sel, gx, gy, gz, A.scr, 25, slot);
}

// ---------- dist1 (scattered) ----------
__global__ __launch_bounds__(256) void dist1(const float4* __restrict__ X1,
                                             const float4* __restrict__ Y1,
                                             float* __restrict__ scr, float ie2) {
  int lane = threadIdx.x & 63, wid = threadIdx.x >> 6;
  int slot = ((blockIdx.x << 2) + wid) & 255;
  emd_dist_wave(X1, Y1, 1024, blockIdx.x * 4 + wid, lane, ie2, scr, 0, slot);
}

// ---------- final reduce: scr -> sc ----------
__global__ __launch_bounds__(256) void reduce_sc(const float* __restrict__ scr,
                                                 float* __restrict__ sc) {
  __shared__ float r4[4];
  int t = threadIdx.x, lane = t & 63, wid = t >> 6;
  for (int s = 0; s < 26; ++s) {
    float v = scr[s * 256 + t];
    for (int off = 32; off; off >>= 1) v += __shfl_xor(v, off);
    if (lane == 0) r4[wid] = v;
    __syncthreads();
    if (t == 0) sc[s] = r4[0] + r4[1] + r4[2] + r4[3];
    __syncthreads();
  }
}

// ---------- host launch ----------

extern "C" void kernel_launch(void* const* d_in, const int* in_sizes, int n_in,
                              void* d_out, int out_size, void* d_ws, size_t ws_size,
                              hipStream_t stream) {
  const float* out1 = (const float*)d_in[0];  // (4,1024,3)
  const float* out2 = (const float*)d_in[1];  // (4,4096,3)
  const float* gt   = (const float*)d_in[2];  // (4,4096,3)
  float* out = (float*)d_out;
  const int B = 4, N1 = 1024, N2 = 4096;

  char* ws = (char*)d_ws;
  float*  dl_ws  = (float*)(ws + 0);            // 64K gt-FPS dl state
  int*    far_ws = (int*)(ws + 64 * 1024);
  int*    idx_u1 = (int*)(ws + 66 * 1024);
  int*    idx_u2 = (int*)(ws + 68 * 1024);
  float*  scr    = (float*)(ws + 80 * 1024);    // 26x256 floats
  float4* X1 = (float4*)(ws + 112 * 1024);      // 64K  out1 + f1
  float4* Y1 = (float4*)(ws + 176 * 1024);      // 64K  gtfps + g1
  float4* X2 = (float4*)(ws + 240 * 1024);      // 256K out2 + f2
  float4* Y2 = (float4*)(ws + 496 * 1024);      // 256K gt + g2 -> ends 752K

  float* sc = out + (size_t)B * N1 * 3 + (size_t)B * N2 * 3;

  pack4<<<(36864 + 255) / 256, 256, 0, stream>>>(out1, out2, gt, X1, X2, Y2, out, sc, scr);

  const float ie2 = 200.0f * LOG2E;
  const float eps_ln2 = 0.005f * LN2;
  float c1 = (float)(0.005 * (-log((double)N1)));
  float c2 = (float)(0.005 * (-log((double)N2)));

  // gt-FPS schedule: mega1 [1,204); EMD2 launch k (k=0..19): [204+41k, +41) -> 1024.
  // EMD1 chain carries NO FPS (R14).
  const int GT_M = 204, CH2 = 41;

  Mega1Args M1;
  M1.X1 = X1; M1.X2 = X2; M1.Y2 = Y2; M1.Y1 = Y1;
  M1.dlws = dl_ws; M1.farws = far_ws;
  M1.idx_u1 = idx_u1; M1.idx_u2 = idx_u2; M1.scr = scr;
  M1.gt_it1 = GT_M;
  mega1<<<12 + 3328, 512, 0, stream>>>(M1);

  // uniform params
  const double PCT[5] = {0.004, 0.006, 0.008, 0.01, 0.012};
  int np1 = 51, np2 = 204;
  UniP P1, P2;
  for (int k = 0; k < 5; ++k) {
    double p = PCT[k];
    {
      int ns = (int)((double)N1 * p);
      double r = sqrt(p * 1.0);
      double el = sqrt(M_PI * 1.0 * p / (double)ns);
      P1.r2[k] = (float)(r * r); P1.ns[k] = ns;
      P1.exlen[k] = (float)el;   P1.exden[k] = (float)(el + 1e-8);
      P1.wg[k] = (float)((p * 100.0) * (p * 100.0) / (5.0 * (double)B * (double)np1));
    }
    {
      int ns = (int)((double)N2 * p);
      double r = sqrt(p * 1.0);
      double el = sqrt(M_PI * 1.0 * p / (double)ns);
      P2.r2[k] = (float)(r * r); P2.ns[k] = ns;
      P2.exlen[k] = (float)el;   P2.exden[k] = (float)(el + 1e-8);
      P2.wg[k] = (float)((p * 100.0) * (p * 100.0) / (5.0 * (double)B * (double)np2));
    }
  }

  SinkUArgs SA;
  SA.gt4 = Y2; SA.dlws = dl_ws; SA.farws = far_ws; SA.Y1 = Y1;
  SA.ie2 = ie2; SA.eps_ln2 = eps_ln2;
  SA.o1raw = out1; SA.o2raw = out2; SA.iu1 = idx_u1; SA.iu2 = idx_u2;
  SA.P1 = P1; SA.P2 = P2; SA.scr = scr;
  SA.dX = X2; SA.dY = Y2; SA.dN = N2; SA.dbase = 4;

  // EMD2 chain: 20 launches, 4 FPS[41] + 256 sink + 32 uniform blocks each.
  // Grid = 4+256+32 = 292 <= 512 (one co-residency round at 55KB).
  SA.N = N2; SA.c = c2; SA.nfps = 4; SA.nsink = 256; SA.d2_0 = 0; SA.d2_n = 0;
  int chunk = 0, uni_done = 0;
  for (int it = 0; it < 10; ++it) {
    for (int half = 0; half < 2; ++half) {
      SA.Pout = half ? X2 : Y2;
      SA.Pred = half ? (const float4*)Y2 : (const float4*)X2;
      SA.it0 = GT_M + CH2 * chunk;
      SA.it1 = SA.it0 + CH2;
      chunk++;
      int un = 32;  // 20 x 32 = 640 >= 638; task guard no-ops the overhang
      SA.uni0 = uni_done;
      uni_done += un;
      sinku<<<4 + 256 + un, 512, 0, stream>>>(SA);
    }
  }

  // EMD1 chain: Y1 complete now. 20 launches, 0 FPS + 64 sink blocks + dist2 slices.
  SA.N = N1; SA.c = c1; SA.nfps = 0; SA.nsink = 64;
  SA.it0 = 0; SA.it1 = 0;
  int d2_done = 0;
  for (int it = 0; it < 10; ++it) {
    for (int half = 0; half < 2; ++half) {
      SA.Pout = half ? X1 : Y1;
      SA.Pred = half ? (const float4*)Y1 : (const float4*)X1;
      int dn = (2048 - d2_done < 103) ? 2048 - d2_done : 103;
      SA.d2_0 = d2_done; SA.d2_n = dn;
      d2_done += dn;
      SA.uni0 = 640;  // none
      sinku<<<64 + dn, 512, 0, stream>>>(SA);
    }
  }

  dist1<<<1024, 256, 0, stream>>>(X1, Y1, scr, ie2);
  reduce_sc<<<1, 256, 0, stream>>>(scr, sc);
}

// Round 9
// 1120.685 us; speedup vs baseline: 2.4087x; 1.1239x over previous
//
#include <hip/hip_runtime.h>
#include <math.h>

// ---------- helpers ----------

extern "C" __device__ float __ocml_native_exp2_f32(float);

__device__ __forceinline__ float sq3_rn(float ax, float ay, float az,
                                        float bx, float by, float bz) {
  float dx = __fsub_rn(ax, bx), dy = __fsub_rn(ay, by), dz = __fsub_rn(az, bz);
  return __fadd_rn(__fadd_rn(__fmul_rn(dx, dx), __fmul_rn(dy, dy)), __fmul_rn(dz, dz));
}

__device__ __forceinline__ float norm3_rn(float x, float y, float z) {
  return __fadd_rn(__fadd_rn(__fmul_rn(x, x), __fmul_rn(y, y)), __fmul_rn(z, z));
}

__device__ __forceinline__ float ex2(float x) {
#if __has_builtin(__builtin_amdgcn_exp2f)
  return __builtin_amdgcn_exp2f(x);
#else
  return __ocml_native_exp2_f32(x);
#endif
}
__device__ __forceinline__ float lg2(float x) { return __builtin_log2f(x); }

#define LOG2E 1.44269504088896340736f
#define LN2   0.69314718055994530942f

// DPP-based wave64 max over u64 keys (R21): VALU-speed reduce replacing the
// 6x ds_swizzle-routed __shfl_xor chain (~240-400cyc -> ~100-120cyc).
// CTRL is a template param — __builtin_amdgcn_update_dpp REQUIRES an immediate
// constant (R8 compile failure: runtime arg rejected even when inlined).
// row_shr:1,2,4,8 accumulate the row-of-16 max into lane15/31/47/63;
// row_bcast:15 merges rows 0->1, 2->3; row_bcast:31 merges halves
// (lane63 = full-wave max). Invalid lanes read old = own key (coherent lo/hi),
// safe for max. Max is associative+exact, so the (max bv, min idx) winner —
// and thus the FPS selection sequence — is IDENTICAL to the shfl version.
template <int CTRL>
__device__ __forceinline__ unsigned long long dpp_pair_max(unsigned long long k) {
  int lo = (int)(unsigned)k;
  int hi = (int)(unsigned)(k >> 32);
  int plo = __builtin_amdgcn_update_dpp(lo, lo, CTRL, 0xf, 0xf, false);
  int phi = __builtin_amdgcn_update_dpp(hi, hi, CTRL, 0xf, 0xf, false);
  unsigned long long p = ((unsigned long long)(unsigned)phi << 32) | (unsigned)plo;
  return p > k ? p : k;
}

__device__ __forceinline__ unsigned long long wave_max_key(unsigned long long key) {
  key = dpp_pair_max<0x111>(key);  // row_shr:1
  key = dpp_pair_max<0x112>(key);  // row_shr:2
  key = dpp_pair_max<0x114>(key);  // row_shr:4
  key = dpp_pair_max<0x118>(key);  // row_shr:8
  key = dpp_pair_max<0x142>(key);  // row_bcast:15
  key = dpp_pair_max<0x143>(key);  // row_bcast:31
  return key;  // lane 63 holds the wave max
}

// sc[26]: emd1=0..3, emd2=4..7, cdp1=8, cdp2=12, cdt1=16, cdt2=20, u1=24, u2=25.
// Scatter: scr[s*256 + slot] (R13). DEPENDENCY (R14): gt-FPS rides only non-Y1 launches.
// R15/R16: fps_body stays the R0 LDS-points loop (register restructure = 1.45x slower,
//          measured twice). R17: sink halves stay under the FPS umbrella (moving them out
//          exposes ~10-11us each — measured twice). R18: grid.sync ~80us — ruled out.
// R19/R6: per-launch fixed cost small; CH2=41 x 20 is the measured-optimal schedule.
// R20 LESSON: FPS must NOT read arrays whose .w is concurrently sink-written (L2 line
//          contention on the critical path); keep FPS on the raw const inputs.
// R21: ONLY change vs the 1201.9us R1 config — the DPP wave-reduce above.

// ---------- pack + passthrough + zero sc/scr ----------
__global__ void pack4(const float* __restrict__ out1, const float* __restrict__ out2,
                      const float* __restrict__ gt,
                      float4* __restrict__ X1, float4* __restrict__ X2, float4* __restrict__ Y2,
                      float* __restrict__ outdst, float* __restrict__ sc,
                      float* __restrict__ scr) {
  int i = blockIdx.x * 256 + threadIdx.x;
  if (i < 26) sc[i] = 0.f;
  if (i < 6656) scr[i] = 0.f;
  if (i < 4096) {
    const float* s = out1 + 3 * (size_t)i;
    float x = s[0], y = s[1], z = s[2];
    X1[i] = make_float4(x, y, z, 0.f);
    float* d = outdst + 3 * (size_t)i;
    d[0] = x; d[1] = y; d[2] = z;
  } else if (i < 20480) {
    int j = i - 4096;
    const float* s = out2 + 3 * (size_t)j;
    float x = s[0], y = s[1], z = s[2];
    X2[j] = make_float4(x, y, z, 0.f);
    float* d = outdst + 12288 + 3 * (size_t)j;
    d[0] = x; d[1] = y; d[2] = z;
  } else if (i < 36864) {
    int j = i - 20480;
    const float* s = gt + 3 * (size_t)j;
    Y2[j] = make_float4(s[0], s[1], s[2], 0.f);
  }
}

// ---------- FPS body: R6-proven 512-thread core + chunk/resume (R0 + DPP reduce) ----------
template <int PPT>
__device__ void fps_body(const float* __restrict__ xb, int it0, int it1,
                         float* __restrict__ dlws, int* __restrict__ farws,
                         bool fresh, bool save,
                         float4* __restrict__ y1g, int* __restrict__ idxg,
                         float* spx, float* spy, float* spz,
                         int* obs, unsigned long long* red /*[16]*/) {
  int t = threadIdx.x;  // 0..511
  float rx[PPT], ry[PPT], rz[PPT], dl[PPT];
#pragma unroll
  for (int j = 0; j < PPT; ++j) {
    int n = t + (j << 9);
    float x = xb[3 * n], y = xb[3 * n + 1], z = xb[3 * n + 2];
    rx[j] = x; ry[j] = y; rz[j] = z;
    spx[n] = x; spy[n] = y; spz[n] = z;
  }
  if (fresh) {
#pragma unroll
    for (int j = 0; j < PPT; ++j) dl[j] = 1e10f;
  } else {
#pragma unroll
    for (int j = 0; j < PPT; ++j) dl[j] = dlws[(j << 9) + t];
  }
  int far = fresh ? 0 : farws[0];
  if (fresh && t == 0) {
    if (y1g) y1g[0] = make_float4(xb[0], xb[1], xb[2], 0.f);
    if (idxg) idxg[0] = 0;
  }
  __syncthreads();
  int lane = t & 63, wid = t >> 6;
  for (int it = it0; it < it1; ++it) {
    float cx = spx[far], cy = spy[far], cz = spz[far];  // wave-uniform broadcast reads
    float bv = -1.f; int bi = 0;
#pragma unroll
    for (int j = 0; j < PPT; ++j) {
      int n = t + (j << 9);
      float d = sq3_rn(rx[j], ry[j], rz[j], cx, cy, cz);
      float dn = fminf(dl[j], d);
      dl[j] = dn;
      bool c = dn > bv;  // strict > with ascending n => first-index local tiebreak
      bv = c ? dn : bv;
      bi = c ? n : bi;
    }
    unsigned long long key =
        ((unsigned long long)__float_as_uint(bv) << 32) | (unsigned)(0x7fffffff - bi);
    key = wave_max_key(key);  // R21: DPP reduce; lane 63 holds wave max
    unsigned long long* rb = red + ((it & 1) << 3);
    if (lane == 63) rb[wid] = key;
    __syncthreads();
    unsigned long long k0 = rb[0], k1 = rb[1], k2 = rb[2], k3 = rb[3];
    unsigned long long k4 = rb[4], k5 = rb[5], k6 = rb[6], k7 = rb[7];
    unsigned long long a0 = k0 > k1 ? k0 : k1, a1 = k2 > k3 ? k2 : k3;
    unsigned long long a2 = k4 > k5 ? k4 : k5, a3 = k6 > k7 ? k6 : k7;
    unsigned long long b0 = a0 > a1 ? a0 : a1, b1 = a2 > a3 ? a2 : a3;
    unsigned long long kk = b0 > b1 ? b0 : b1;
    far = 0x7fffffff - (int)(unsigned)(kk & 0xffffffffULL);  // all threads agree
    if (t == 0) obs[it - it0] = far;
  }
  __syncthreads();
  int cnt = it1 - it0;
  if (y1g)
    for (int i = t; i < cnt; i += 512) {
      int j = obs[i];
      y1g[it0 + i] = make_float4(spx[j], spy[j], spz[j], 0.f);
    }
  if (idxg)
    for (int i = t; i < cnt; i += 512) idxg[it0 + i] = obs[i];
  if (save) {
#pragma unroll
    for (int j = 0; j < PPT; ++j) dlws[(j << 9) + t] = dl[j];
    if (t == 0) farws[0] = far;
  }
}

// ---------- chamfer: 2 rows per wave, scattered atomics ----------
__device__ void chamfer_wave2(const float4* __restrict__ A, const float4* __restrict__ Bp,
                              int Na, int Nb, int w, int lane,
                              float* __restrict__ scr, int sp_s, int st_s, int slot) {
  int rows = Na >> 1;
  int b = w / rows, i0 = (w - b * rows) << 1;
  float4 a0 = A[(size_t)b * Na + i0];
  float4 a1 = A[(size_t)b * Na + i0 + 1];
  const float4* pb = Bp + (size_t)b * Nb;
  float mn0 = 3.4e38f, mn1 = 3.4e38f;
  for (int j = lane; j < Nb; j += 64) {
    float4 p = pb[j];
    float dx0 = p.x - a0.x, dy0 = p.y - a0.y, dz0 = p.z - a0.z;
    mn0 = fminf(mn0, dx0 * dx0 + dy0 * dy0 + dz0 * dz0);
    float dx1 = p.x - a1.x, dy1 = p.y - a1.y, dz1 = p.z - a1.z;
    mn1 = fminf(mn1, dx1 * dx1 + dy1 * dy1 + dz1 * dz1);
  }
  for (int off = 32; off; off >>= 1) {
    mn0 = fminf(mn0, __shfl_xor(mn0, off));
    mn1 = fminf(mn1, __shfl_xor(mn1, off));
  }
  if (lane == 0) {
    atomicAdd(&scr[(sp_s + b) * 256 + slot], 0.5f * (sqrtf(mn0) + sqrtf(mn1)) * (1.f / (float)Na));
    atomicAdd(&scr[(st_s + b) * 256 + slot], (mn0 + mn1) * (1.f / (float)Na));
  }
}

// ---------- mega1: gt-FPS chunk0 + out1/out2 FPS + all chamfer (512-thr, 55KB) ----------
struct Mega1Args {
  const float *gt, *out1, *out2;
  const float4 *X1, *X2, *Y2;
  float4* Y1;
  float* dlws; int* farws;
  int* idx_u1; int* idx_u2;
  float* scr;
  int gt_it1;
};

__global__ __launch_bounds__(512) void mega1(Mega1Args A) {
  __shared__ __align__(16) unsigned char sm[55296];
  float* spx = (float*)sm;
  float* spy = (float*)(sm + 16384);
  float* spz = (float*)(sm + 32768);
  int* obs = (int*)(sm + 49152);
  unsigned long long* red = (unsigned long long*)(sm + 53248);
  int blk = blockIdx.x;
  int t = threadIdx.x;
  if (blk < 4) {  // gt-FPS chunk0 [1, gt_it1), fresh, save
    __builtin_amdgcn_s_setprio(3);  // serial critical path
    int b = blk;
    fps_body<8>(A.gt + (size_t)b * 4096 * 3, 1, A.gt_it1,
                A.dlws + (size_t)b * 4096, A.farws + b, true, true,
                A.Y1 + (size_t)b * 1024, nullptr, spx, spy, spz, obs, red);
    return;
  }
  if (blk < 8) {  // out2-FPS full 204
    __builtin_amdgcn_s_setprio(3);
    int b = blk - 4;
    fps_body<8>(A.out2 + (size_t)b * 4096 * 3, 1, 204, nullptr, nullptr, true, false,
                nullptr, A.idx_u2 + (size_t)b * 204, spx, spy, spz, obs, red);
    return;
  }
  if (blk < 12) {  // out1-FPS full 51
    __builtin_amdgcn_s_setprio(3);
    int b = blk - 8;
    fps_body<2>(A.out1 + (size_t)b * 1024 * 3, 1, 51, nullptr, nullptr, true, false,
                nullptr, A.idx_u1 + (size_t)b * 51, spx, spy, spz, obs, red);
    return;
  }
  __builtin_amdgcn_s_setprio(0);
  int lane = t & 63, wid = t >> 6;
  int slot = ((blk << 3) + wid) & 255;
  int wt = (blk - 12) * 8 + wid;  // 26624 wave-tasks over 3328 blocks
  if (wt < 8192)        chamfer_wave2(A.Y2, A.X1, 4096, 1024, wt,         lane, A.scr, 8, 16, slot);
  else if (wt < 10240)  chamfer_wave2(A.X1, A.Y2, 1024, 4096, wt - 8192,  lane, A.scr, 8, 16, slot);
  else if (wt < 18432)  chamfer_wave2(A.Y2, A.X2, 4096, 4096, wt - 10240, lane, A.scr, 12, 20, slot);
  else                  chamfer_wave2(A.X2, A.Y2, 4096, 4096, wt - 18432, lane, A.scr, 12, 20, slot);
}

// ---------- sink wave: 8 outputs, no-max (bounded args), SoA LDS tile (R13-validated) ----------
__device__ void sink_wave8(float4* __restrict__ Pout, const float4* __restrict__ Pred,
                           int N, float c, int w0, float ie2, float eps_ln2,
                           float* xs, float* ys, float* zs, float* ws4, int nthr) {
  int t = threadIdx.x, lane = t & 63;
  int b = w0 / N, o0 = w0 - b * N;
  float qx[8], qy[8], qz[8], Bc[8], S[8];
  float two_ie = 2.f * ie2;
#pragma unroll
  for (int r = 0; r < 8; ++r) {
    float4 m = Pout[(size_t)b * N + o0 + r];
    qx[r] = two_ie * m.x; qy[r] = two_ie * m.y; qz[r] = two_ie * m.z;
    Bc[r] = -ie2 * (m.x * m.x + m.y * m.y + m.z * m.z);
    S[r] = 0.f;
  }
  const float4* Rb = Pred + (size_t)b * N;
  for (int base = 0; base < N; base += 1024) {
    __syncthreads();
    for (int i = t; i < 1024; i += nthr) {
      float4 p = Rb[base + i];
      xs[i] = p.x; ys[i] = p.y; zs[i] = p.z;
      ws4[i] = (p.w - fmaf(p.z, p.z, fmaf(p.y, p.y, p.x * p.x))) * ie2;
    }
    __syncthreads();
#pragma unroll
    for (int k = 0; k < 16; ++k) {
      int idx = lane + (k << 6);
      float px = xs[idx], py = ys[idx], pz = zs[idx], pw = ws4[idx];
#pragma unroll
      for (int r = 0; r < 8; ++r)
        S[r] += ex2(fmaf(pz, qz[r], fmaf(py, qy[r], fmaf(px, qx[r], pw + Bc[r]))));
    }
  }
#pragma unroll
  for (int r = 0; r < 8; ++r)
    for (int off = 32; off; off >>= 1) S[r] += __shfl_xor(S[r], off);
  if (lane == 0) {
#pragma unroll
    for (int r = 0; r < 8; ++r)
      Pout[(size_t)b * N + o0 + r].w = c - eps_ln2 * lg2(S[r]);
  }
}

// ---------- EMD distance wave (scattered) ----------
__device__ void emd_dist_wave(const float4* __restrict__ X, const float4* __restrict__ Y,
                              int N, int task, int lane, float ie2,
                              float* __restrict__ scr, int base_s, int slot) {
  int b = task / N, n = task - b * N;
  float4 mine = X[(size_t)b * N + n];
  const float4* Yb = Y + (size_t)b * N;
  float acc = 0.f;
  for (int m = lane; m < N; m += 64) {
    float4 p = Yb[m];
    float dx = p.x - mine.x, dy = p.y - mine.y, dz = p.z - mine.z;
    float d = dx * dx + dy * dy + dz * dz;
    acc += ex2((mine.w + p.w - d) * ie2) * d;
  }
  for (int off = 32; off; off >>= 1) acc += __shfl_xor(acc, off);
  if (lane == 0)
    atomicAdd(&scr[(base_s + b) * 256 + slot], sqrtf((float)N * acc) * (1.f / (float)N));
}

// ---------- uniform loss wave (bit-exact discrete path, scattered) ----------
struct UniP {
  float r2[5]; int ns[5]; float exden[5]; float exlen[5]; float wg[5];
};

__device__ void uniform_wave(const float* __restrict__ pcd, const int* __restrict__ fpsidx,
                             int N, int npoint, const UniP& P, int task, int lane,
                             int* sel, float* gx, float* gy, float* gz,
                             float* __restrict__ scr, int us, int slot) {
  int pi = task % 5;
  int tmp = task / 5;
  int s = tmp % npoint;
  int b = tmp / npoint;
  int nsample = P.ns[pi];
  float r2 = P.r2[pi];
  const float* Pb = pcd + (size_t)b * N * 3;
  int sidx = fpsidx[b * npoint + s];
  float sx = Pb[3 * sidx], sy = Pb[3 * sidx + 1], sz = Pb[3 * sidx + 2];
  float snorm = norm3_rn(sx, sy, sz);

  int cnt = 0;
  for (int base = 0; base < N && cnt < nsample; base += 64) {
    int n = base + lane;
    float pxn = Pb[3 * n], pyn = Pb[3 * n + 1], pzn = Pb[3 * n + 2];
    float pn2 = norm3_rn(pxn, pyn, pzn);
    float dot = __fadd_rn(__fadd_rn(__fmul_rn(sx, pxn), __fmul_rn(sy, pyn)), __fmul_rn(sz, pzn));
    float d2 = fmaxf(__fsub_rn(__fadd_rn(snorm, pn2), __fmul_rn(2.f, dot)), 0.f);
    unsigned long long bal = __ballot(d2 < r2);
    while (bal && cnt < nsample) {
      int bit = __builtin_ctzll(bal);
      if (lane == 0) sel[cnt] = base + bit;
      cnt++;
      bal &= bal - 1;
    }
  }
  if (lane < nsample) {
    int gi = (lane < cnt) ? sel[lane] : sel[0];
    gx[lane] = Pb[3 * gi]; gy[lane] = Pb[3 * gi + 1]; gz[lane] = Pb[3 * gi + 2];
  }
  float dval = 0.f;
  if (lane < nsample) {
    float mn = 1e10f;
    for (int k = 0; k < nsample; ++k) {
      if (k == lane) continue;
      float dx = gx[lane] - gx[k], dy = gy[lane] - gy[k], dz = gz[lane] - gz[k];
      float d = dx * dx + dy * dy + dz * dz;
      mn = fminf(mn, d);
    }
    dval = sqrtf(fabsf(mn + 1e-8f));
  }
  for (int off = 32; off; off >>= 1) dval += __shfl_xor(dval, off);
  if (lane == 0) {
    float mean_d = dval / (float)nsample;
    float diff = mean_d - P.exlen[pi];
    atomicAdd(&scr[us * 256 + slot], diff * diff / P.exden[pi] * P.wg[pi]);
  }
}

// ---------- sinku: [nfps FPS chunks] + sink half-pass + dist2 slice + uniform slice ----------
// 512-thr, 55KB LDS (2 blocks/CU). GRID MUST BE <= 512 BLOCKS (one co-residency round).
struct SinkUArgs {
  float4* Pout; const float4* Pred; int N; float c; int nfps, nsink;
  const float* gt; float* dlws; int* farws; float4* Y1;
  int it0, it1;
  const float4 *dX, *dY; int dN, dbase, d2_0, d2_n;
  const float *o1raw, *o2raw;
  const int *iu1, *iu2;
  UniP P1, P2;
  int uni0;
  float* scr;
  float ie2, eps_ln2;
};

__global__ __launch_bounds__(512) void sinku(SinkUArgs A) {
  __shared__ __align__(16) unsigned char sm[55296];
  int blk = blockIdx.x;
  int t = threadIdx.x, lane = t & 63, wid = t >> 6;
  if (blk < A.nfps) {  // gt-FPS chunk (resume) — only on launches that don't touch Y1
    __builtin_amdgcn_s_setprio(3);
    float* spx = (float*)sm;
    float* spy = (float*)(sm + 16384);
    float* spz = (float*)(sm + 32768);
    int* obs = (int*)(sm + 49152);
    unsigned long long* red = (unsigned long long*)(sm + 53248);
    int b = blk;
    fps_body<8>(A.gt + (size_t)b * 4096 * 3, A.it0, A.it1,
                A.dlws + (size_t)b * 4096, A.farws + b, false, true,
                A.Y1 + (size_t)b * 1024, nullptr, spx, spy, spz, obs, red);
    return;
  }
  __builtin_amdgcn_s_setprio(0);
  float* smf = (float*)sm;
  if (blk < A.nfps + A.nsink) {
    int sblk = blk - A.nfps;
    int w0 = ((sblk << 3) + wid) << 3;  // 8 waves x 8 outputs = 64 outputs/block
    sink_wave8(A.Pout, A.Pred, A.N, A.c, w0, A.ie2, A.eps_ln2,
               smf, smf + 1024, smf + 2048, smf + 3072, 512);
    return;
  }
  int slot = ((blk << 3) + wid) & 255;
  if (blk < A.nfps + A.nsink + A.d2_n) {
    int dblk = A.d2_0 + (blk - A.nfps - A.nsink);
    emd_dist_wave(A.dX, A.dY, A.dN, dblk * 8 + wid, lane, A.ie2, A.scr, A.dbase, slot);
    return;
  }
  // uniform: 8 tasks per block
  int ublk = blk - (A.nfps + A.nsink + A.d2_n);
  int task = (A.uni0 + ublk) * 8 + wid;
  float* sl = smf + wid * 256;
  int* sel = (int*)sl;
  float* gx = smf + 2048 + wid * 256;
  float* gy = smf + 4096 + wid * 256;
  float* gz = smf + 6144 + wid * 256;
  if (task < 1020)
    uniform_wave(A.o1raw, A.iu1, 1024, 51, A.P1, task, lane, sel, gx, gy, gz, A.scr, 24, slot);
  else if (task < 5100)
    uniform_wave(A.o2raw, A.iu2, 4096, 204, A.P2, task - 1020, lane, sel, gx, gy, gz, A.scr, 25, slot);
}

// ---------- dist1 (scattered) ----------
__global__ __launch_bounds__(256) void dist1(const float4* __restrict__ X1,
                                             const float4* __restrict__ Y1,
                                             float* __restrict__ scr, float ie2) {
  int lane = threadIdx.x & 63, wid = threadIdx.x >> 6;
  int slot = ((blockIdx.x << 2) + wid) & 255;
  emd_dist_wave(X1, Y1, 1024, blockIdx.x * 4 + wid, lane, ie2, scr, 0, slot);
}

// ---------- final reduce: scr -> sc ----------
__global__ __launch_bounds__(256) void reduce_sc(const float* __restrict__ scr,
                                                 float* __restrict__ sc) {
  __shared__ float r4[4];
  int t = threadIdx.x, lane = t & 63, wid = t >> 6;
  for (int s = 0; s < 26; ++s) {
    float v = scr[s * 256 + t];
    for (int off = 32; off; off >>= 1) v += __shfl_xor(v, off);
    if (lane == 0) r4[wid] = v;
    __syncthreads();
    if (t == 0) sc[s] = r4[0] + r4[1] + r4[2] + r4[3];
    __syncthreads();
  }
}

// ---------- host launch ----------

extern "C" void kernel_launch(void* const* d_in, const int* in_sizes, int n_in,
                              void* d_out, int out_size, void* d_ws, size_t ws_size,
                              hipStream_t stream) {
  const float* out1 = (const float*)d_in[0];  // (4,1024,3)
  const float* out2 = (const float*)d_in[1];  // (4,4096,3)
  const float* gt   = (const float*)d_in[2];  // (4,4096,3)
  float* out = (float*)d_out;
  const int B = 4, N1 = 1024, N2 = 4096;

  char* ws = (char*)d_ws;
  float*  dl_ws  = (float*)(ws + 0);            // 64K gt-FPS dl state
  int*    far_ws = (int*)(ws + 64 * 1024);
  int*    idx_u1 = (int*)(ws + 66 * 1024);
  int*    idx_u2 = (int*)(ws + 68 * 1024);
  float*  scr    = (float*)(ws + 80 * 1024);    // 26x256 floats
  float4* X1 = (float4*)(ws + 112 * 1024);      // 64K  out1 + f1
  float4* Y1 = (float4*)(ws + 176 * 1024);      // 64K  gtfps + g1
  float4* X2 = (float4*)(ws + 240 * 1024);      // 256K out2 + f2
  float4* Y2 = (float4*)(ws + 496 * 1024);      // 256K gt + g2 -> ends 752K

  float* sc = out + (size_t)B * N1 * 3 + (size_t)B * N2 * 3;

  pack4<<<(36864 + 255) / 256, 256, 0, stream>>>(out1, out2, gt, X1, X2, Y2, out, sc, scr);

  const float ie2 = 200.0f * LOG2E;
  const float eps_ln2 = 0.005f * LN2;
  float c1 = (float)(0.005 * (-log((double)N1)));
  float c2 = (float)(0.005 * (-log((double)N2)));

  // gt-FPS schedule: mega1 [1,204); EMD2 launch k (k=0..19): [204+41k, +41) -> 1024.
  // EMD1 chain carries NO FPS (it reads/writes Y1 — R14 race lesson).
  const int GT_M = 204, CH2 = 41;

  Mega1Args M1;
  M1.gt = gt; M1.out1 = out1; M1.out2 = out2;
  M1.X1 = X1; M1.X2 = X2; M1.Y2 = Y2; M1.Y1 = Y1;
  M1.dlws = dl_ws; M1.farws = far_ws;
  M1.idx_u1 = idx_u1; M1.idx_u2 = idx_u2; M1.scr = scr;
  M1.gt_it1 = GT_M;
  mega1<<<12 + 3328, 512, 0, stream>>>(M1);

  // uniform params
  const double PCT[5] = {0.004, 0.006, 0.008, 0.01, 0.012};
  int np1 = 51, np2 = 204;
  UniP P1, P2;
  for (int k = 0; k < 5; ++k) {
    double p = PCT[k];
    {
      int ns = (int)((double)N1 * p);
      double r = sqrt(p * 1.0);
      double el = sqrt(M_PI * 1.0 * p / (double)ns);
      P1.r2[k] = (float)(r * r); P1.ns[k] = ns;
      P1.exlen[k] = (float)el;   P1.exden[k] = (float)(el + 1e-8);
      P1.wg[k] = (float)((p * 100.0) * (p * 100.0) / (5.0 * (double)B * (double)np1));
    }
    {
      int ns = (int)((double)N2 * p);
      double r = sqrt(p * 1.0);
      double el = sqrt(M_PI * 1.0 * p / (double)ns);
      P2.r2[k] = (float)(r * r); P2.ns[k] = ns;
      P2.exlen[k] = (float)el;   P2.exden[k] = (float)(el + 1e-8);
      P2.wg[k] = (float)((p * 100.0) * (p * 100.0) / (5.0 * (double)B * (double)np2));
    }
  }

  SinkUArgs SA;
  SA.gt = gt; SA.dlws = dl_ws; SA.farws = far_ws; SA.Y1 = Y1;
  SA.ie2 = ie2; SA.eps_ln2 = eps_ln2;
  SA.o1raw = out1; SA.o2raw = out2; SA.iu1 = idx_u1; SA.iu2 = idx_u2;
  SA.P1 = P1; SA.P2 = P2; SA.scr = scr;
  SA.dX = X2; SA.dY = Y2; SA.dN = N2; SA.dbase = 4;

  // EMD2 chain: 20 launches, 4 FPS + 256 sink blocks + uniform slices.
  // Grid <= 4+256+213 = 473 <= 512 (one co-residency round at 55KB).
  const int UNI_BLOCKS = 638;
  SA.N = N2; SA.c = c2; SA.nfps = 4; SA.nsink = 256; SA.d2_0 = 0; SA.d2_n = 0;
  int chunk = 0, uni_done = 0;
  for (int it = 0; it < 10; ++it) {
    for (int half = 0; half < 2; ++half) {
      SA.Pout = half ? X2 : Y2;
      SA.Pred = half ? (const float4*)Y2 : (const float4*)X2;
      SA.it0 = GT_M + CH2 * chunk;
      SA.it1 = SA.it0 + CH2;
      chunk++;
      int un = 0;
      if (uni_done < UNI_BLOCKS) un = (UNI_BLOCKS - uni_done < 213) ? UNI_BLOCKS - uni_done : 213;
      SA.uni0 = uni_done;
      uni_done += un;
      sinku<<<4 + 256 + un, 512, 0, stream>>>(SA);
    }
  }

  // EMD1 chain: Y1 complete now. 20 launches, 0 FPS + 64 sink blocks + dist2 slices.
  SA.N = N1; SA.c = c1; SA.nfps = 0; SA.nsink = 64;
  SA.it0 = 0; SA.it1 = 0;
  int d2_done = 0;
  for (int it = 0; it < 10; ++it) {
    for (int half = 0; half < 2; ++half) {
      SA.Pout = half ? X1 : Y1;
      SA.Pred = half ? (const float4*)Y1 : (const float4*)X1;
      int dn = (2048 - d2_done < 103) ? 2048 - d2_done : 103;
      SA.d2_0 = d2_done; SA.d2_n = dn;
      d2_done += dn;
      SA.uni0 = UNI_BLOCKS;  // none
      sinku<<<64 + dn, 512, 0, stream>>>(SA);
    }
  }

  dist1<<<1024, 256, 0, stream>>>(X1, Y1, scr, ie2);
  reduce_sc<<<1, 256, 0, stream>>>(scr, sc);
}